// Round 1
// baseline (4822.912 us; speedup 1.0000x reference)
//
#include <hip/hip_runtime.h>
#include <stdint.h>

#define B_ 128
#define S_ 512
#define I_ 128
#define H_ 256

typedef short bf16x8 __attribute__((ext_vector_type(8)));
typedef float f32x4  __attribute__((ext_vector_type(4)));

__device__ __forceinline__ short f2bf(float f){
  unsigned u = __float_as_uint(f);
  u = (u + 0x7FFFu + ((u >> 16) & 1u)) >> 16;
  return (short)u;
}
__device__ __forceinline__ float sigmoidf_(float x){
  float e = __expf(-x);
  return __fdividef(1.f, 1.f + e);
}
__device__ __forceinline__ float tanhf_(float x){
  x = fminf(fmaxf(x, -10.f), 10.f);
  float e = __expf(2.f * x);
  return __fdividef(e - 1.f, e + 1.f);
}

// ---------------- prep: combined input weights Wc = W_in @ Wg0_top, biases ----
__global__ __launch_bounds__(256) void prep_compute(
    const float* __restrict__ W_in, const float* __restrict__ b_in,
    const float* __restrict__ Wz, const float* __restrict__ bz,
    const float* __restrict__ Wr, const float* __restrict__ br,
    const float* __restrict__ Wn, const float* __restrict__ bn,
    float* __restrict__ WcT, float* __restrict__ bc, float* __restrict__ bcat1)
{
  int id = blockIdx.x * 256 + threadIdx.x;
  if (id < 98304){                       // Wc[i][gcol] = sum_j W_in[i][j]*Wg[0][j][n]
    int i = id / 768, gcol = id % 768;
    int g = gcol >> 8, n = gcol & 255;
    const float* Wg = (g == 0) ? Wz : (g == 1) ? Wr : Wn;
    float s = 0.f;
    for (int j = 0; j < 256; j++) s += W_in[i * 256 + j] * Wg[j * 256 + n];
    WcT[i * 768 + gcol] = s;
  } else if (id < 99072){                // bc[gcol] = b_in @ Wg0_top + bg0
    int gcol = id - 98304;
    int g = gcol >> 8, n = gcol & 255;
    const float* Wg = (g == 0) ? Wz : (g == 1) ? Wr : Wn;
    const float* bg = (g == 0) ? bz : (g == 1) ? br : bn;
    float s = 0.f;
    for (int j = 0; j < 256; j++) s += b_in[j] * Wg[j * 256 + n];
    bc[gcol] = s + bg[n];
  } else if (id < 99840){                // bcat1[gcol] = bg[1][n]
    int gcol = id - 99072;
    int g = gcol >> 8, n = gcol & 255;
    const float* bg = (g == 0) ? bz : (g == 1) ? br : bn;
    bcat1[gcol] = bg[256 + n];
  }
}

// ---------------- fragment packing -------------------------------------------
// B-frag layout (matches mfma_f32_16x16x32_bf16, m92/m97-verified contiguous-k):
//   frag(nt,kt): lane l, elem j holds B[kt*32 + (l>>4)*8 + j][nt*16 + (l&15)]
//   stored at dst[(((nt*KT + kt)*64 + l)*8 + j)]

__global__ __launch_bounds__(256) void pack_wc(short* __restrict__ dst, const float* __restrict__ WcT)
{
  int id = blockIdx.x * 256 + threadIdx.x;           // 98304 = 48nt * 4kt * 64 * 8
  int j = id & 7, l = (id >> 3) & 63, kt = (id >> 9) & 3, nt = id >> 11;
  int k = kt * 32 + (l >> 4) * 8 + j;
  int gcol = nt * 16 + (l & 15);
  dst[id] = f2bf(WcT[k * 768 + gcol]);
}

__global__ __launch_bounds__(256) void pack_top(short* __restrict__ dst,
    const float* __restrict__ Wz, const float* __restrict__ Wr, const float* __restrict__ Wn)
{
  int id = blockIdx.x * 256 + threadIdx.x;           // 196608 = 48nt * 8kt * 64 * 8
  int j = id & 7, l = (id >> 3) & 63, kt = (id >> 9) & 7, nt = id >> 12;
  int k = kt * 32 + (l >> 4) * 8 + j;                // 0..255  (layer-1 top half)
  int gcol = nt * 16 + (l & 15);
  int g = gcol >> 8, n = gcol & 255;
  const float* W = (g == 0) ? Wz : (g == 1) ? Wr : Wn;
  dst[id] = f2bf(W[(size_t)(512 + k) * 256 + n]);
}

__global__ __launch_bounds__(256) void pack_zr(short* __restrict__ dst,
    const float* __restrict__ Wz, const float* __restrict__ Wr, int layer)
{
  int id = blockIdx.x * 256 + threadIdx.x;           // 131072 = 32nt * 8kt * 64 * 8
  int j = id & 7, l = (id >> 3) & 63, kt = (id >> 9) & 7, nt = id >> 12;
  int k = kt * 32 + (l >> 4) * 8 + j;                // bottom half (h part)
  int n = (nt & 15) * 16 + (l & 15);
  const float* W = (nt < 16) ? Wz : Wr;
  dst[id] = f2bf(W[((size_t)layer * 512 + 256 + k) * 256 + n]);
}

__global__ __launch_bounds__(256) void pack_n(short* __restrict__ dst,
    const float* __restrict__ Wn, int layer)
{
  int id = blockIdx.x * 256 + threadIdx.x;           // 65536 = 16nt * 8kt * 64 * 8
  int j = id & 7, l = (id >> 3) & 63, kt = (id >> 9) & 7, nt = id >> 12;
  int k = kt * 32 + (l >> 4) * 8 + j;
  int n = nt * 16 + (l & 15);
  dst[id] = f2bf(Wn[((size_t)layer * 512 + 256 + k) * 256 + n]);
}

// ---------------- big parallel GEMM: C[M,768] = A[M,K] @ Bfrags + bias --------
template<bool ABF16, int KT>
__global__ __launch_bounds__(256) void gemm_kernel(
    const void* __restrict__ Ap, const short* __restrict__ BF,
    const float* __restrict__ bias, float* __restrict__ C)
{
  const int tid = threadIdx.x, w = tid >> 6, l = tid & 63;
  const int m0 = blockIdx.x * 64 + w * 16;
  const int nb = blockIdx.y;
  const int K = KT * 32;
  f32x4 zero4 = {0.f, 0.f, 0.f, 0.f};
  f32x4 acc[8];
#pragma unroll
  for (int nt = 0; nt < 8; nt++) acc[nt] = zero4;

#pragma unroll
  for (int kt = 0; kt < KT; kt++){
    bf16x8 af;
    if (ABF16){
      af = *(const bf16x8*)((const short*)Ap + (size_t)(m0 + (l & 15)) * K + kt * 32 + (l >> 4) * 8);
    } else {
      const float* A = (const float*)Ap + (size_t)(m0 + (l & 15)) * K + kt * 32 + (l >> 4) * 8;
      f32x4 a0 = *(const f32x4*)A;
      f32x4 a1 = *(const f32x4*)(A + 4);
      af[0] = f2bf(a0[0]); af[1] = f2bf(a0[1]); af[2] = f2bf(a0[2]); af[3] = f2bf(a0[3]);
      af[4] = f2bf(a1[0]); af[5] = f2bf(a1[1]); af[6] = f2bf(a1[2]); af[7] = f2bf(a1[3]);
    }
#pragma unroll
    for (int nt = 0; nt < 8; nt++){
      bf16x8 bf = *(const bf16x8*)(BF + (size_t)(((nb * 8 + nt) * KT + kt) * 64 + l) * 8);
      acc[nt] = __builtin_amdgcn_mfma_f32_16x16x32_bf16(af, bf, acc[nt], 0, 0, 0);
    }
  }
#pragma unroll
  for (int nt = 0; nt < 8; nt++){
    int col = nb * 128 + nt * 16 + (l & 15);
    float bv = bias[col];
#pragma unroll
    for (int rr = 0; rr < 4; rr++){
      int mrow = m0 + (l >> 4) * 4 + rr;
      C[(size_t)mrow * 768 + col] = acc[nt][rr] + bv;
    }
  }
}

// ---------------- persistent recurrent core ----------------------------------
// 8 blocks x 512 threads (8 waves). Block = 16 batch rows. Weights in VGPRs.
// h fp32 in registers; activations broadcast via XOR-swizzled LDS (bf16).
template<bool OUT_BF16>
__global__ __launch_bounds__(512) void recur_kernel(
    const float* __restrict__ G,        // [B*S][768] precomputed input+bias parts
    const short* __restrict__ WzrF,     // fused z|r bottom-half frags NT=32 KT=8
    const short* __restrict__ WnF,      // n bottom-half frags NT=16 KT=8
    void* __restrict__ outp,            // bf16 pipe or fp32 d_out, [b][t][256]
    float* __restrict__ finals)         // [128][256] slice of h_final
{
  __shared__ __align__(16) short hA[4096];   // h_prev bf16 [16][256], swizzled
  __shared__ __align__(16) short rA[4096];   // r*h_prev bf16, swizzled

  const int tid = threadIdx.x;
  const int w = tid >> 6, l = tid & 63;
  const int r0 = blockIdx.x * 16;
  const int cix = l & 15, lk = l >> 4;

  bf16x8 wzr[4][8];
  bf16x8 wn[2][8];
#pragma unroll
  for (int i = 0; i < 4; i++)
#pragma unroll
    for (int kt = 0; kt < 8; kt++)
      wzr[i][kt] = *(const bf16x8*)(WzrF + (size_t)((((w + 8 * i) * 8 + kt) * 64 + l) * 8));
#pragma unroll
  for (int i = 0; i < 2; i++)
#pragma unroll
    for (int kt = 0; kt < 8; kt++)
      wn[i][kt] = *(const bf16x8*)(WnF + (size_t)((((w + 8 * i) * 8 + kt) * 64 + l) * 8));

  {
    bf16x8 z8 = {0,0,0,0,0,0,0,0};
    *(bf16x8*)(hA + tid * 8) = z8;
  }
  __syncthreads();

  float h[2][4];
#pragma unroll
  for (int i = 0; i < 2; i++)
#pragma unroll
    for (int rr = 0; rr < 4; rr++) h[i][rr] = 0.f;

  f32x4 zero4 = {0.f, 0.f, 0.f, 0.f};

  for (int t = 0; t < S_; t++){
    // --- precomputed gate parts (z, r now; n later) ---
    float gz[2][4], gr[2][4];
#pragma unroll
    for (int rr = 0; rr < 4; rr++){
      const float* gp = G + ((size_t)(r0 + lk * 4 + rr) * S_ + t) * 768;
#pragma unroll
      for (int i = 0; i < 2; i++){
        int cc = (w + 8 * i) * 16 + cix;
        gz[i][rr] = gp[cc];
        gr[i][rr] = gp[256 + cc];
      }
    }
    // --- M_zr: [16,256] @ [256,512] ---
    f32x4 acc[4];
#pragma unroll
    for (int i = 0; i < 4; i++) acc[i] = zero4;
#pragma unroll
    for (int kt = 0; kt < 8; kt++){
      bf16x8 af = *(const bf16x8*)((const char*)hA + cix * 512 + ((kt * 64 + lk * 16) ^ ((cix & 7) << 4)));
#pragma unroll
      for (int i = 0; i < 4; i++)
        acc[i] = __builtin_amdgcn_mfma_f32_16x16x32_bf16(af, wzr[i][kt], acc[i], 0, 0, 0);
    }
    float zv[2][4], rv[2][4];
#pragma unroll
    for (int i = 0; i < 2; i++)
#pragma unroll
      for (int rr = 0; rr < 4; rr++){
        zv[i][rr] = sigmoidf_(acc[i][rr] + gz[i][rr]);
        rv[i][rr] = sigmoidf_(acc[2 + i][rr] + gr[i][rr]);
      }
    // --- write r*h_prev (bf16, swizzled) ---
#pragma unroll
    for (int i = 0; i < 2; i++)
#pragma unroll
      for (int rr = 0; rr < 4; rr++){
        int row = lk * 4 + rr, col = (w + 8 * i) * 16 + cix;
        *(short*)((char*)rA + row * 512 + ((col * 2) ^ ((row & 7) << 4))) = f2bf(rv[i][rr] * h[i][rr]);
      }
    __syncthreads();
    // --- M_n: [16,256] @ [256,256] ---
    float gn[2][4];
#pragma unroll
    for (int rr = 0; rr < 4; rr++){
      const float* gp = G + ((size_t)(r0 + lk * 4 + rr) * S_ + t) * 768;
#pragma unroll
      for (int i = 0; i < 2; i++)
        gn[i][rr] = gp[512 + (w + 8 * i) * 16 + cix];
    }
    f32x4 acc2[2];
#pragma unroll
    for (int i = 0; i < 2; i++) acc2[i] = zero4;
#pragma unroll
    for (int kt = 0; kt < 8; kt++){
      bf16x8 af = *(const bf16x8*)((const char*)rA + cix * 512 + ((kt * 64 + lk * 16) ^ ((cix & 7) << 4)));
#pragma unroll
      for (int i = 0; i < 2; i++)
        acc2[i] = __builtin_amdgcn_mfma_f32_16x16x32_bf16(af, wn[i][kt], acc2[i], 0, 0, 0);
    }
    // --- h update + outputs ---
#pragma unroll
    for (int i = 0; i < 2; i++)
#pragma unroll
      for (int rr = 0; rr < 4; rr++){
        int row = lk * 4 + rr, col = (w + 8 * i) * 16 + cix;
        float nv = tanhf_(acc2[i][rr] + gn[i][rr]);
        float hn = (1.f - zv[i][rr]) * nv + zv[i][rr] * h[i][rr];
        h[i][rr] = hn;
        *(short*)((char*)hA + row * 512 + ((col * 2) ^ ((row & 7) << 4))) = f2bf(hn);
        size_t oidx = ((size_t)(r0 + row) * S_ + t) * H_ + col;
        if (OUT_BF16) ((short*)outp)[oidx] = f2bf(hn);
        else          ((float*)outp)[oidx] = hn;
      }
    __syncthreads();
  }
  // finals (fp32 from registers)
#pragma unroll
  for (int i = 0; i < 2; i++)
#pragma unroll
    for (int rr = 0; rr < 4; rr++){
      int row = lk * 4 + rr, col = (w + 8 * i) * 16 + cix;
      finals[(size_t)(r0 + row) * H_ + col] = h[i][rr];
    }
}

// ---------------- launcher ----------------------------------------------------
extern "C" void kernel_launch(void* const* d_in, const int* in_sizes, int n_in,
                              void* d_out, int out_size, void* d_ws, size_t ws_size,
                              hipStream_t stream)
{
  (void)in_sizes; (void)n_in; (void)out_size; (void)ws_size;
  const float* x    = (const float*)d_in[0];
  const float* W_in = (const float*)d_in[1];
  const float* b_in = (const float*)d_in[2];
  const float* Wz   = (const float*)d_in[3];
  const float* bz   = (const float*)d_in[4];
  const float* Wr   = (const float*)d_in[5];
  const float* br   = (const float*)d_in[6];
  const float* Wn   = (const float*)d_in[7];
  const float* bn   = (const float*)d_in[8];
  float* out = (float*)d_out;

  char* ws = (char*)d_ws;
  float* Gbuf  = (float*)(ws + 0);            // [65536][768] fp32, reused for G0 then P1
  float* WcT   = (float*)(ws + 201326592);    // [128][768] fp32 tmp
  float* bc    = (float*)(ws + 201719808);    // [768]
  float* bcat1 = (float*)(ws + 201722880);    // [768]
  short* WCF   = (short*)(ws + 201725952);    // Wc frags (NT=48,KT=4)
  short* W1TF  = (short*)(ws + 201922560);    // layer1 top frags (NT=48,KT=8)
  short* WZR0  = (short*)(ws + 202315776);    // layer0 zr bottom frags
  short* WN0   = (short*)(ws + 202577920);    // layer0 n bottom frags
  short* WZR1  = (short*)(ws + 202708992);
  short* WN1   = (short*)(ws + 202971136);
  short* pipe  = (short*)(ws + 203102208);    // h0 sequence bf16 [b][t][256]

  prep_compute<<<390, 256, 0, stream>>>(W_in, b_in, Wz, bz, Wr, br, Wn, bn, WcT, bc, bcat1);
  pack_wc <<<384, 256, 0, stream>>>(WCF, WcT);
  pack_top<<<768, 256, 0, stream>>>(W1TF, Wz, Wr, Wn);
  pack_zr <<<512, 256, 0, stream>>>(WZR0, Wz, Wr, 0);
  pack_n  <<<256, 256, 0, stream>>>(WN0, Wn, 0);
  pack_zr <<<512, 256, 0, stream>>>(WZR1, Wz, Wr, 1);
  pack_n  <<<256, 256, 0, stream>>>(WN1, Wn, 1);

  // G0 = x @ Wc + bc   (layer-0 input-half, all steps)
  gemm_kernel<false, 4><<<dim3(1024, 6), 256, 0, stream>>>(x, WCF, bc, Gbuf);
  // layer 0 recurrence -> h0 pipe (bf16) + h_final[0]
  recur_kernel<true><<<8, 512, 0, stream>>>(Gbuf, WZR0, WN0, pipe, out + 16777216);
  // P1 = h0 @ W1_top + b1  (layer-1 input-half, all steps)
  gemm_kernel<true, 8><<<dim3(1024, 6), 256, 0, stream>>>(pipe, W1TF, bcat1, Gbuf);
  // layer 1 recurrence -> outputs (fp32) + h_final[1]
  recur_kernel<false><<<8, 512, 0, stream>>>(Gbuf, WZR1, WN1, out, out + 16777216 + 32768);
}

// Round 2
// 3136.573 us; speedup vs baseline: 1.5376x; 1.5376x over previous
//
#include <hip/hip_runtime.h>
#include <stdint.h>

#define B_ 128
#define S_ 512
#define I_ 128
#define H_ 256

#define R_  2          // batch rows per recurrent block
#define NB_ (B_ / R_)  // 64 recurrent blocks

typedef short bf16x8 __attribute__((ext_vector_type(8)));
typedef float f32x4  __attribute__((ext_vector_type(4)));

__device__ __forceinline__ short f2bf(float f){
  unsigned u = __float_as_uint(f);
  u = (u + 0x7FFFu + ((u >> 16) & 1u)) >> 16;
  return (short)u;
}
__device__ __forceinline__ float bf2f(unsigned short u){
  return __uint_as_float(((unsigned)u) << 16);
}
__device__ __forceinline__ float sigmoidf_(float x){
  float e = __expf(-x);
  return __fdividef(1.f, 1.f + e);
}
__device__ __forceinline__ float tanhf_(float x){
  x = fminf(fmaxf(x, -10.f), 10.f);
  float e = __expf(2.f * x);
  return __fdividef(e - 1.f, e + 1.f);
}
// raw barrier: order LDS ops, do NOT drain vmcnt (keeps global prefetch in flight)
__device__ __forceinline__ void bar_lds(){
  asm volatile("s_waitcnt lgkmcnt(0)" ::: "memory");
  __builtin_amdgcn_s_barrier();
}

// ---------------- prep: combined input weights Wc = W_in @ Wg0_top, biases ----
__global__ __launch_bounds__(256) void prep_compute(
    const float* __restrict__ W_in, const float* __restrict__ b_in,
    const float* __restrict__ Wz, const float* __restrict__ bz,
    const float* __restrict__ Wr, const float* __restrict__ br,
    const float* __restrict__ Wn, const float* __restrict__ bn,
    float* __restrict__ WcT, float* __restrict__ bc, float* __restrict__ bcat1)
{
  int id = blockIdx.x * 256 + threadIdx.x;
  if (id < 98304){                       // Wc[i][gcol] = sum_j W_in[i][j]*Wg[0][j][n]
    int i = id / 768, gcol = id % 768;
    int g = gcol >> 8, n = gcol & 255;
    const float* Wg = (g == 0) ? Wz : (g == 1) ? Wr : Wn;
    float s = 0.f;
    for (int j = 0; j < 256; j++) s += W_in[i * 256 + j] * Wg[j * 256 + n];
    WcT[i * 768 + gcol] = s;
  } else if (id < 99072){                // bc[gcol] = b_in @ Wg0_top + bg0
    int gcol = id - 98304;
    int g = gcol >> 8, n = gcol & 255;
    const float* Wg = (g == 0) ? Wz : (g == 1) ? Wr : Wn;
    const float* bg = (g == 0) ? bz : (g == 1) ? br : bn;
    float s = 0.f;
    for (int j = 0; j < 256; j++) s += b_in[j] * Wg[j * 256 + n];
    bc[gcol] = s + bg[n];
  } else if (id < 99840){                // bcat1[gcol] = bg[1][n]
    int gcol = id - 99072;
    int g = gcol >> 8, n = gcol & 255;
    const float* bg = (g == 0) ? bz : (g == 1) ? br : bn;
    bcat1[gcol] = bg[256 + n];
  }
}

// ---------------- fragment packing -------------------------------------------
// B-frag layout (mfma_f32_16x16x32_bf16): lane l, elem j holds
//   B[kt*32 + (l>>4)*8 + j][nt*16 + (l&15)], stored dst[(((nt*KT+kt)*64+l)*8+j)]

__global__ __launch_bounds__(256) void pack_wc(short* __restrict__ dst, const float* __restrict__ WcT)
{
  int id = blockIdx.x * 256 + threadIdx.x;           // 98304 = 48nt * 4kt * 64 * 8
  int j = id & 7, l = (id >> 3) & 63, kt = (id >> 9) & 3, nt = id >> 11;
  int k = kt * 32 + (l >> 4) * 8 + j;
  int gcol = nt * 16 + (l & 15);
  dst[id] = f2bf(WcT[k * 768 + gcol]);
}

__global__ __launch_bounds__(256) void pack_top(short* __restrict__ dst,
    const float* __restrict__ Wz, const float* __restrict__ Wr, const float* __restrict__ Wn)
{
  int id = blockIdx.x * 256 + threadIdx.x;           // 196608 = 48nt * 8kt * 64 * 8
  int j = id & 7, l = (id >> 3) & 63, kt = (id >> 9) & 7, nt = id >> 12;
  int k = kt * 32 + (l >> 4) * 8 + j;                // 0..255  (layer-1 top half)
  int gcol = nt * 16 + (l & 15);
  int g = gcol >> 8, n = gcol & 255;
  const float* W = (g == 0) ? Wz : (g == 1) ? Wr : Wn;
  dst[id] = f2bf(W[(size_t)(512 + k) * 256 + n]);
}

__global__ __launch_bounds__(256) void pack_zr(short* __restrict__ dst,
    const float* __restrict__ Wz, const float* __restrict__ Wr, int layer)
{
  int id = blockIdx.x * 256 + threadIdx.x;           // 131072 = 32nt * 8kt * 64 * 8
  int j = id & 7, l = (id >> 3) & 63, kt = (id >> 9) & 7, nt = id >> 12;
  int k = kt * 32 + (l >> 4) * 8 + j;                // bottom half (h part)
  int n = (nt & 15) * 16 + (l & 15);
  const float* W = (nt < 16) ? Wz : Wr;
  dst[id] = f2bf(W[((size_t)layer * 512 + 256 + k) * 256 + n]);
}

__global__ __launch_bounds__(256) void pack_n(short* __restrict__ dst,
    const float* __restrict__ Wn, int layer)
{
  int id = blockIdx.x * 256 + threadIdx.x;           // 65536 = 16nt * 8kt * 64 * 8
  int j = id & 7, l = (id >> 3) & 63, kt = (id >> 9) & 7, nt = id >> 12;
  int k = kt * 32 + (l >> 4) * 8 + j;
  int n = nt * 16 + (l & 15);
  dst[id] = f2bf(Wn[((size_t)layer * 512 + 256 + k) * 256 + n]);
}

// ---------------- big parallel GEMM: C[M,768] = A[M,K] @ Bfrags + bias --------
// output bf16 (consumed by recur kernels)
template<bool ABF16, int KT>
__global__ __launch_bounds__(256) void gemm_kernel(
    const void* __restrict__ Ap, const short* __restrict__ BF,
    const float* __restrict__ bias, short* __restrict__ C)
{
  const int tid = threadIdx.x, w = tid >> 6, l = tid & 63;
  const int m0 = blockIdx.x * 64 + w * 16;
  const int nb = blockIdx.y;
  const int K = KT * 32;
  f32x4 zero4 = {0.f, 0.f, 0.f, 0.f};
  f32x4 acc[8];
#pragma unroll
  for (int nt = 0; nt < 8; nt++) acc[nt] = zero4;

#pragma unroll
  for (int kt = 0; kt < KT; kt++){
    bf16x8 af;
    if (ABF16){
      af = *(const bf16x8*)((const short*)Ap + (size_t)(m0 + (l & 15)) * K + kt * 32 + (l >> 4) * 8);
    } else {
      const float* A = (const float*)Ap + (size_t)(m0 + (l & 15)) * K + kt * 32 + (l >> 4) * 8;
      f32x4 a0 = *(const f32x4*)A;
      f32x4 a1 = *(const f32x4*)(A + 4);
      af[0] = f2bf(a0[0]); af[1] = f2bf(a0[1]); af[2] = f2bf(a0[2]); af[3] = f2bf(a0[3]);
      af[4] = f2bf(a1[0]); af[5] = f2bf(a1[1]); af[6] = f2bf(a1[2]); af[7] = f2bf(a1[3]);
    }
#pragma unroll
    for (int nt = 0; nt < 8; nt++){
      bf16x8 bf = *(const bf16x8*)(BF + (size_t)(((nb * 8 + nt) * KT + kt) * 64 + l) * 8);
      acc[nt] = __builtin_amdgcn_mfma_f32_16x16x32_bf16(af, bf, acc[nt], 0, 0, 0);
    }
  }
#pragma unroll
  for (int nt = 0; nt < 8; nt++){
    int col = nb * 128 + nt * 16 + (l & 15);
    float bv = bias[col];
#pragma unroll
    for (int rr = 0; rr < 4; rr++){
      int mrow = m0 + (l >> 4) * 4 + rr;
      C[(size_t)mrow * 768 + col] = f2bf(acc[nt][rr] + bv);
    }
  }
}

// ---------------- persistent recurrent core ----------------------------------
// NB_ blocks x 512 threads (8 waves). Block = R_ batch rows (M-tile underfilled:
// LDS rows >= R_ stay zero -> those lanes compute exact zeros, discarded).
// Weights in VGPRs/AGPRs; h fp32 in registers; activations via swizzled LDS.
// G (bf16) register-prefetched one step ahead; raw barriers keep vmcnt alive.
template<bool OUT_BF16>
__global__ __launch_bounds__(512) void recur_kernel(
    const unsigned short* __restrict__ G,  // [B][S][768] bf16 precomputed gate input-half
    const short* __restrict__ WzrF,        // fused z|r bottom-half frags NT=32 KT=8
    const short* __restrict__ WnF,         // n bottom-half frags NT=16 KT=8
    void* __restrict__ outp,               // bf16 pipe or fp32 d_out, [b][t][256]
    float* __restrict__ finals)            // [128][256] slice of h_final
{
  __shared__ __align__(16) short hA[4096];   // h_prev bf16 [16][256], swizzled
  __shared__ __align__(16) short rA[4096];   // r*h_prev bf16, swizzled

  const int tid = threadIdx.x;
  const int w = tid >> 6, l = tid & 63;
  const int r0 = blockIdx.x * R_;
  const int cix = l & 15, lk = l >> 4;

  bf16x8 wzr[4][8];
  bf16x8 wn[2][8];
#pragma unroll
  for (int i = 0; i < 4; i++)
#pragma unroll
    for (int kt = 0; kt < 8; kt++)
      wzr[i][kt] = *(const bf16x8*)(WzrF + (size_t)((((w + 8 * i) * 8 + kt) * 64 + l) * 8));
#pragma unroll
  for (int i = 0; i < 2; i++)
#pragma unroll
    for (int kt = 0; kt < 8; kt++)
      wn[i][kt] = *(const bf16x8*)(WnF + (size_t)((((w + 8 * i) * 8 + kt) * 64 + l) * 8));

  {
    bf16x8 z8 = {0,0,0,0,0,0,0,0};
    *(bf16x8*)(hA + tid * 8) = z8;
    *(bf16x8*)(rA + tid * 8) = z8;
  }

  float h[2][4];
#pragma unroll
  for (int i = 0; i < 2; i++)
#pragma unroll
    for (int rr = 0; rr < 4; rr++) h[i][rr] = 0.f;

  // G prefetch registers: [gate z/r/n][i][rr<R_]; only lanes lk==0 load real
  // values, all others stay 0 (their MFMA rows are zero too).
  float gc[3][2][R_], gnx[3][2][R_];
#pragma unroll
  for (int g3 = 0; g3 < 3; g3++)
#pragma unroll
    for (int i = 0; i < 2; i++)
#pragma unroll
      for (int rr = 0; rr < R_; rr++){ gc[g3][i][rr] = 0.f; gnx[g3][i][rr] = 0.f; }

#define LOADG(T, garr) do { \
  if (lk == 0){ \
    _Pragma("unroll") \
    for (int rr = 0; rr < R_; rr++){ \
      const unsigned short* gp = G + ((size_t)(r0 + rr) * S_ + (T)) * 768; \
      _Pragma("unroll") \
      for (int i = 0; i < 2; i++){ \
        int cc = (w + 8 * i) * 16 + cix; \
        garr[0][i][rr] = bf2f(gp[cc]); \
        garr[1][i][rr] = bf2f(gp[256 + cc]); \
        garr[2][i][rr] = bf2f(gp[512 + cc]); \
      } } } } while(0)

  LOADG(0, gc);
  bar_lds();

  f32x4 zero4 = {0.f, 0.f, 0.f, 0.f};

  for (int t = 0; t < S_; t++){
    // issue next-step G loads (consumed next iteration; stays in flight across
    // raw barriers since we never drain vmcnt)
    int tn = (t + 1 < S_) ? t + 1 : t;
    LOADG(tn, gnx);

    // --- M_zr: [16,256] @ [256,512] ---
    f32x4 acc[4];
#pragma unroll
    for (int i = 0; i < 4; i++) acc[i] = zero4;
#pragma unroll
    for (int kt = 0; kt < 8; kt++){
      bf16x8 af = *(const bf16x8*)((const char*)hA + cix * 512 + ((kt * 64 + lk * 16) ^ ((cix & 7) << 4)));
#pragma unroll
      for (int i = 0; i < 4; i++)
        acc[i] = __builtin_amdgcn_mfma_f32_16x16x32_bf16(af, wzr[i][kt], acc[i], 0, 0, 0);
    }
    float zv[2][4], rv[2][4];
#pragma unroll
    for (int i = 0; i < 2; i++)
#pragma unroll
      for (int rr = 0; rr < 4; rr++){
        float gz = (rr < R_) ? gc[0][i][rr] : 0.f;
        float gr = (rr < R_) ? gc[1][i][rr] : 0.f;
        zv[i][rr] = sigmoidf_(acc[i][rr] + gz);
        rv[i][rr] = sigmoidf_(acc[2 + i][rr] + gr);
      }
    // --- write r*h_prev (bf16, swizzled); only real rows ---
    if (lk == 0){
#pragma unroll
      for (int i = 0; i < 2; i++)
#pragma unroll
        for (int rr = 0; rr < R_; rr++){
          int row = rr, col = (w + 8 * i) * 16 + cix;
          *(short*)((char*)rA + row * 512 + ((col * 2) ^ ((row & 7) << 4))) = f2bf(rv[i][rr] * h[i][rr]);
        }
    }
    bar_lds();
    // --- M_n: [16,256] @ [256,256] ---
    f32x4 acc2[2];
#pragma unroll
    for (int i = 0; i < 2; i++) acc2[i] = zero4;
#pragma unroll
    for (int kt = 0; kt < 8; kt++){
      bf16x8 af = *(const bf16x8*)((const char*)rA + cix * 512 + ((kt * 64 + lk * 16) ^ ((cix & 7) << 4)));
#pragma unroll
      for (int i = 0; i < 2; i++)
        acc2[i] = __builtin_amdgcn_mfma_f32_16x16x32_bf16(af, wn[i][kt], acc2[i], 0, 0, 0);
    }
    // --- h update + outputs ---
#pragma unroll
    for (int i = 0; i < 2; i++)
#pragma unroll
      for (int rr = 0; rr < 4; rr++){
        float gn = (rr < R_) ? gc[2][i][rr] : 0.f;
        float nv = tanhf_(acc2[i][rr] + gn);
        h[i][rr] = (1.f - zv[i][rr]) * nv + zv[i][rr] * h[i][rr];
      }
    if (lk == 0){
#pragma unroll
      for (int i = 0; i < 2; i++)
#pragma unroll
        for (int rr = 0; rr < R_; rr++){
          int row = rr, col = (w + 8 * i) * 16 + cix;
          float hn = h[i][rr];
          *(short*)((char*)hA + row * 512 + ((col * 2) ^ ((row & 7) << 4))) = f2bf(hn);
          size_t oidx = ((size_t)(r0 + row) * S_ + t) * H_ + col;
          if (OUT_BF16) ((short*)outp)[oidx] = f2bf(hn);
          else          ((float*)outp)[oidx] = hn;
        }
    }
    // advance prefetch
#pragma unroll
    for (int g3 = 0; g3 < 3; g3++)
#pragma unroll
      for (int i = 0; i < 2; i++)
#pragma unroll
        for (int rr = 0; rr < R_; rr++) gc[g3][i][rr] = gnx[g3][i][rr];
    bar_lds();
  }
#undef LOADG
  // finals (fp32 from registers)
  if (lk == 0){
#pragma unroll
    for (int i = 0; i < 2; i++)
#pragma unroll
      for (int rr = 0; rr < R_; rr++){
        int row = rr, col = (w + 8 * i) * 16 + cix;
        finals[(size_t)(r0 + row) * H_ + col] = h[i][rr];
      }
  }
}

// ---------------- launcher ----------------------------------------------------
extern "C" void kernel_launch(void* const* d_in, const int* in_sizes, int n_in,
                              void* d_out, int out_size, void* d_ws, size_t ws_size,
                              hipStream_t stream)
{
  (void)in_sizes; (void)n_in; (void)out_size; (void)ws_size;
  const float* x    = (const float*)d_in[0];
  const float* W_in = (const float*)d_in[1];
  const float* b_in = (const float*)d_in[2];
  const float* Wz   = (const float*)d_in[3];
  const float* bz   = (const float*)d_in[4];
  const float* Wr   = (const float*)d_in[5];
  const float* br   = (const float*)d_in[6];
  const float* Wn   = (const float*)d_in[7];
  const float* bn   = (const float*)d_in[8];
  float* out = (float*)d_out;

  char* ws = (char*)d_ws;
  short* Gbuf  = (short*)(ws + 0);            // [65536][768] bf16, reused G0 then P1
  float* WcT   = (float*)(ws + 201326592);    // [128][768] fp32 tmp
  float* bc    = (float*)(ws + 201719808);    // [768]
  float* bcat1 = (float*)(ws + 201722880);    // [768]
  short* WCF   = (short*)(ws + 201725952);    // Wc frags (NT=48,KT=4)
  short* W1TF  = (short*)(ws + 201922560);    // layer1 top frags (NT=48,KT=8)
  short* WZR0  = (short*)(ws + 202315776);    // layer0 zr bottom frags
  short* WN0   = (short*)(ws + 202577920);    // layer0 n bottom frags
  short* WZR1  = (short*)(ws + 202708992);
  short* WN1   = (short*)(ws + 202971136);
  short* pipe  = (short*)(ws + 203102208);    // h0 sequence bf16 [b][t][256]

  prep_compute<<<390, 256, 0, stream>>>(W_in, b_in, Wz, bz, Wr, br, Wn, bn, WcT, bc, bcat1);
  pack_wc <<<384, 256, 0, stream>>>(WCF, WcT);
  pack_top<<<768, 256, 0, stream>>>(W1TF, Wz, Wr, Wn);
  pack_zr <<<512, 256, 0, stream>>>(WZR0, Wz, Wr, 0);
  pack_n  <<<256, 256, 0, stream>>>(WN0, Wn, 0);
  pack_zr <<<512, 256, 0, stream>>>(WZR1, Wz, Wr, 1);
  pack_n  <<<256, 256, 0, stream>>>(WN1, Wn, 1);

  // G0 = x @ Wc + bc   (layer-0 input-half, all steps) -> bf16
  gemm_kernel<false, 4><<<dim3(1024, 6), 256, 0, stream>>>(x, WCF, bc, Gbuf);
  // layer 0 recurrence -> h0 pipe (bf16) + h_final[0]
  recur_kernel<true><<<NB_, 512, 0, stream>>>((const unsigned short*)Gbuf, WZR0, WN0, pipe, out + 16777216);
  // P1 = h0 @ W1_top + b1  (layer-1 input-half, all steps) -> bf16
  gemm_kernel<true, 8><<<dim3(1024, 6), 256, 0, stream>>>(pipe, W1TF, bcat1, Gbuf);
  // layer 1 recurrence -> outputs (fp32) + h_final[1]
  recur_kernel<false><<<NB_, 512, 0, stream>>>((const unsigned short*)Gbuf, WZR1, WN1, out, out + 16777216 + 32768);
}

// Round 3
// 2534.475 us; speedup vs baseline: 1.9029x; 1.2376x over previous
//
#include <hip/hip_runtime.h>
#include <stdint.h>

#define B_ 128
#define S_ 512
#define I_ 128
#define H_ 256

#define R_  2          // batch rows per recurrent block
#define NB_ (B_ / R_)  // 64 recurrent blocks

typedef short bf16x8 __attribute__((ext_vector_type(8)));
typedef short bf16x4 __attribute__((ext_vector_type(4)));
typedef float f32x4  __attribute__((ext_vector_type(4)));

__device__ __forceinline__ short f2bf(float f){
  unsigned u = __float_as_uint(f);
  u = (u + 0x7FFFu + ((u >> 16) & 1u)) >> 16;
  return (short)u;
}
__device__ __forceinline__ float bf2f(unsigned short u){
  return __uint_as_float(((unsigned)u) << 16);
}
__device__ __forceinline__ float sigmoidf_(float x){
  float e = __expf(-x);
  return __fdividef(1.f, 1.f + e);
}
__device__ __forceinline__ float tanhf_(float x){
  x = fminf(fmaxf(x, -10.f), 10.f);
  float e = __expf(2.f * x);
  return __fdividef(e - 1.f, e + 1.f);
}
// raw barrier: order LDS ops, do NOT drain vmcnt (keeps global prefetch in flight)
__device__ __forceinline__ void bar_lds(){
  asm volatile("s_waitcnt lgkmcnt(0)" ::: "memory");
  __builtin_amdgcn_s_barrier();
}

// ---------------- prep: combined input weights Wc = W_in @ Wg0_top, biases ----
__global__ __launch_bounds__(256) void prep_compute(
    const float* __restrict__ W_in, const float* __restrict__ b_in,
    const float* __restrict__ Wz, const float* __restrict__ bz,
    const float* __restrict__ Wr, const float* __restrict__ br,
    const float* __restrict__ Wn, const float* __restrict__ bn,
    float* __restrict__ WcT, float* __restrict__ bc, float* __restrict__ bcat1)
{
  int id = blockIdx.x * 256 + threadIdx.x;
  if (id < 98304){                       // Wc[i][gcol] = sum_j W_in[i][j]*Wg[0][j][n]
    int i = id / 768, gcol = id % 768;
    int g = gcol >> 8, n = gcol & 255;
    const float* Wg = (g == 0) ? Wz : (g == 1) ? Wr : Wn;
    float s = 0.f;
    for (int j = 0; j < 256; j++) s += W_in[i * 256 + j] * Wg[j * 256 + n];
    WcT[i * 768 + gcol] = s;
  } else if (id < 99072){                // bc[gcol] = b_in @ Wg0_top + bg0
    int gcol = id - 98304;
    int g = gcol >> 8, n = gcol & 255;
    const float* Wg = (g == 0) ? Wz : (g == 1) ? Wr : Wn;
    const float* bg = (g == 0) ? bz : (g == 1) ? br : bn;
    float s = 0.f;
    for (int j = 0; j < 256; j++) s += b_in[j] * Wg[j * 256 + n];
    bc[gcol] = s + bg[n];
  } else if (id < 99840){                // bcat1[gcol] = bg[1][n]
    int gcol = id - 99072;
    int g = gcol >> 8, n = gcol & 255;
    const float* bg = (g == 0) ? bz : (g == 1) ? br : bn;
    bcat1[gcol] = bg[256 + n];
  }
}

// ---------------- fragment packing -------------------------------------------
// B-frag layout (mfma_f32_16x16x32_bf16): lane l, elem j holds
//   B[kt*32 + (l>>4)*8 + j][nt*16 + (l&15)], stored dst[(((nt*KT+kt)*64+l)*8+j)]

__global__ __launch_bounds__(256) void pack_wc(short* __restrict__ dst, const float* __restrict__ WcT)
{
  int id = blockIdx.x * 256 + threadIdx.x;           // 98304 = 48nt * 4kt * 64 * 8
  int j = id & 7, l = (id >> 3) & 63, kt = (id >> 9) & 3, nt = id >> 11;
  int k = kt * 32 + (l >> 4) * 8 + j;
  int gcol = nt * 16 + (l & 15);
  dst[id] = f2bf(WcT[k * 768 + gcol]);
}

__global__ __launch_bounds__(256) void pack_top(short* __restrict__ dst,
    const float* __restrict__ Wz, const float* __restrict__ Wr, const float* __restrict__ Wn)
{
  int id = blockIdx.x * 256 + threadIdx.x;           // 196608 = 48nt * 8kt * 64 * 8
  int j = id & 7, l = (id >> 3) & 63, kt = (id >> 9) & 7, nt = id >> 12;
  int k = kt * 32 + (l >> 4) * 8 + j;                // 0..255  (layer-1 top half)
  int gcol = nt * 16 + (l & 15);
  int g = gcol >> 8, n = gcol & 255;
  const float* W = (g == 0) ? Wz : (g == 1) ? Wr : Wn;
  dst[id] = f2bf(W[(size_t)(512 + k) * 256 + n]);
}

__global__ __launch_bounds__(256) void pack_zr(short* __restrict__ dst,
    const float* __restrict__ Wz, const float* __restrict__ Wr, int layer)
{
  int id = blockIdx.x * 256 + threadIdx.x;           // 131072 = 32nt * 8kt * 64 * 8
  int j = id & 7, l = (id >> 3) & 63, kt = (id >> 9) & 7, nt = id >> 12;
  int k = kt * 32 + (l >> 4) * 8 + j;                // bottom half (h part)
  int n = (nt & 15) * 16 + (l & 15);
  const float* W = (nt < 16) ? Wz : Wr;
  dst[id] = f2bf(W[((size_t)layer * 512 + 256 + k) * 256 + n]);
}

__global__ __launch_bounds__(256) void pack_n(short* __restrict__ dst,
    const float* __restrict__ Wn, int layer)
{
  int id = blockIdx.x * 256 + threadIdx.x;           // 65536 = 16nt * 8kt * 64 * 8
  int j = id & 7, l = (id >> 3) & 63, kt = (id >> 9) & 7, nt = id >> 12;
  int k = kt * 32 + (l >> 4) * 8 + j;
  int n = nt * 16 + (l & 15);
  dst[id] = f2bf(Wn[((size_t)layer * 512 + 256 + k) * 256 + n]);
}

// ---------------- big parallel GEMM: C[M,768] = A[M,K] @ Bfrags + bias --------
// output bf16 [mrow][768]
template<bool ABF16, int KT>
__global__ __launch_bounds__(256) void gemm_kernel(
    const void* __restrict__ Ap, const short* __restrict__ BF,
    const float* __restrict__ bias, short* __restrict__ C)
{
  const int tid = threadIdx.x, w = tid >> 6, l = tid & 63;
  const int m0 = blockIdx.x * 64 + w * 16;
  const int nb = blockIdx.y;
  const int K = KT * 32;
  f32x4 zero4 = {0.f, 0.f, 0.f, 0.f};
  f32x4 acc[8];
#pragma unroll
  for (int nt = 0; nt < 8; nt++) acc[nt] = zero4;

#pragma unroll
  for (int kt = 0; kt < KT; kt++){
    bf16x8 af;
    if (ABF16){
      af = *(const bf16x8*)((const short*)Ap + (size_t)(m0 + (l & 15)) * K + kt * 32 + (l >> 4) * 8);
    } else {
      const float* A = (const float*)Ap + (size_t)(m0 + (l & 15)) * K + kt * 32 + (l >> 4) * 8;
      f32x4 a0 = *(const f32x4*)A;
      f32x4 a1 = *(const f32x4*)(A + 4);
      af[0] = f2bf(a0[0]); af[1] = f2bf(a0[1]); af[2] = f2bf(a0[2]); af[3] = f2bf(a0[3]);
      af[4] = f2bf(a1[0]); af[5] = f2bf(a1[1]); af[6] = f2bf(a1[2]); af[7] = f2bf(a1[3]);
    }
#pragma unroll
    for (int nt = 0; nt < 8; nt++){
      bf16x8 bf = *(const bf16x8*)(BF + (size_t)(((nb * 8 + nt) * KT + kt) * 64 + l) * 8);
      acc[nt] = __builtin_amdgcn_mfma_f32_16x16x32_bf16(af, bf, acc[nt], 0, 0, 0);
    }
  }
#pragma unroll
  for (int nt = 0; nt < 8; nt++){
    int col = nb * 128 + nt * 16 + (l & 15);
    float bv = bias[col];
#pragma unroll
    for (int rr = 0; rr < 4; rr++){
      int mrow = m0 + (l >> 4) * 4 + rr;
      C[(size_t)mrow * 768 + col] = f2bf(acc[nt][rr] + bv);
    }
  }
}

// ---------------- repack Gbuf -> per-thread chunks ---------------------------
// chunk id = blk*65536 + t*128 + w*16 + cix ; values v[rr*6+i*3+gate]
// GpA[id*8+0..7] = v0..7 ; GpB[id*4+0..3] = v8..11
__global__ __launch_bounds__(256) void repack(const unsigned short* __restrict__ Gbuf,
                                              short* __restrict__ GpA, short* __restrict__ GpB)
{
  int id = blockIdx.x * 256 + threadIdx.x;   // 4,194,304 total
  int cix = id & 15, wv = (id >> 4) & 7, t = (id >> 7) & 511, blk = id >> 16;
  short v[12];
#pragma unroll
  for (int rr = 0; rr < 2; rr++)
#pragma unroll
    for (int i = 0; i < 2; i++)
#pragma unroll
      for (int g = 0; g < 3; g++)
        v[rr * 6 + i * 3 + g] =
          (short)Gbuf[((size_t)(2 * blk + rr) * 512 + t) * 768 + g * 256 + i * 128 + wv * 16 + cix];
  bf16x8 a; bf16x4 b;
#pragma unroll
  for (int j = 0; j < 8; j++) a[j] = v[j];
#pragma unroll
  for (int j = 0; j < 4; j++) b[j] = v[8 + j];
  *(bf16x8*)(GpA + (size_t)id * 8) = a;
  *(bf16x4*)(GpB + (size_t)id * 4) = b;
}

// ---------------- persistent recurrent core ----------------------------------
// 64 blocks x 512 threads (8 waves, 2/SIMD, <=256 VGPR: NO SPILLS is the point).
// Block = 2 batch rows. Weights resident in regs (192). LDS 4KB:
//   hA rows 0,1 @ 0/512 ; zero region @1024..1535 ; rA rows @2048/2560 ;
//   (rA-read zero = hA-zero + 2048 = 3072..3583, also zeroed)
// swizzle: (row,col) -> row*512 + (((col>>3)^row)<<4) + (col&7)*2
// A-frag read: lane(cix,lk): cix<2 -> cix*512 + ((kt*4+(lk^cix))<<4) ; else 1024 (bcast zero)
template<bool OUT_BF16>
__global__ __launch_bounds__(512, 2) void recur_kernel(
    const short* __restrict__ GpA, const short* __restrict__ GpB,
    const short* __restrict__ WzrF, const short* __restrict__ WnF,
    void* __restrict__ outp, float* __restrict__ finals)
{
  __shared__ __align__(16) char ldsb[4096];

  const int tid = threadIdx.x;
  const int w = tid >> 6, l = tid & 63;
  const int cix = l & 15, lk = l >> 4;
  const int r0 = blockIdx.x * R_;
  const int chunkBase = blockIdx.x * 65536 + w * 16 + cix;

  // weight fragments (192 VGPR)
  bf16x8 wzr[4][8];
  bf16x8 wn[2][8];
#pragma unroll
  for (int i = 0; i < 4; i++)
#pragma unroll
    for (int kt = 0; kt < 8; kt++)
      wzr[i][kt] = *(const bf16x8*)(WzrF + (size_t)((((w + 8 * i) * 8 + kt) * 64 + l) * 8));
#pragma unroll
  for (int i = 0; i < 2; i++)
#pragma unroll
    for (int kt = 0; kt < 8; kt++)
      wn[i][kt] = *(const bf16x8*)(WnF + (size_t)((((w + 8 * i) * 8 + kt) * 64 + l) * 8));

  // zero all of LDS (h0 = 0, zero-broadcast regions)
  *(uint64_t*)(ldsb + tid * 8) = 0ull;
  __syncthreads();

  // A-frag read base (one reg; per-kt offsets are immediates)
  const int A0 = (cix < 2) ? cix * 512 + ((lk ^ cix) << 4) : 1024;
  // LDS write offsets (row,col) for lk==0 lanes
  const int col0 = w * 16 + cix, col1 = col0 + 128;
  const int oA00 = col0 * 2;                    // row0, i0
  const int oA10 = col1 * 2;                    // row0, i1
  const int oA01 = 512 + ((col0 * 2) ^ 16);     // row1, i0
  const int oA11 = 512 + ((col1 * 2) ^ 16);     // row1, i1

  float h00 = 0.f, h10 = 0.f, h01 = 0.f, h11 = 0.f;  // h[i][rr]

  // G ring, depth 2
  bf16x8 rgA0{}, rgA1{};
  bf16x4 rgB0{}, rgB1{};
  if (lk == 0){
    rgA0 = *(const bf16x8*)(GpA + (size_t)chunkBase * 8);
    rgB0 = *(const bf16x4*)(GpB + (size_t)chunkBase * 4);
    rgA1 = *(const bf16x8*)(GpA + (size_t)(chunkBase + 128) * 8);
    rgB1 = *(const bf16x4*)(GpB + (size_t)(chunkBase + 128) * 4);
  }

  const f32x4 Z4 = {0.f, 0.f, 0.f, 0.f};

#define STEP(T, RGA, RGB) do { \
    float gz00=0.f,gz10=0.f,gz01=0.f,gz11=0.f; \
    float gr00=0.f,gr10=0.f,gr01=0.f,gr11=0.f; \
    float gn00=0.f,gn10=0.f,gn01=0.f,gn11=0.f; \
    if (lk == 0){ \
      gz00=bf2f((unsigned short)RGA[0]); gr00=bf2f((unsigned short)RGA[1]); gn00=bf2f((unsigned short)RGA[2]); \
      gz10=bf2f((unsigned short)RGA[3]); gr10=bf2f((unsigned short)RGA[4]); gn10=bf2f((unsigned short)RGA[5]); \
      gz01=bf2f((unsigned short)RGA[6]); gr01=bf2f((unsigned short)RGA[7]); \
      gn01=bf2f((unsigned short)RGB[0]); gz11=bf2f((unsigned short)RGB[1]); \
      gr11=bf2f((unsigned short)RGB[2]); gn11=bf2f((unsigned short)RGB[3]); \
      int tn = (T) + 2; if (tn >= S_) tn = (T); \
      size_t ch = (size_t)chunkBase + (size_t)tn * 128; \
      RGA = *(const bf16x8*)(GpA + ch * 8); \
      RGB = *(const bf16x4*)(GpB + ch * 4); \
    } \
    f32x4 az0 = Z4, az1 = Z4, ar0 = Z4, ar1 = Z4; \
    _Pragma("unroll") \
    for (int kt = 0; kt < 8; kt++){ \
      bf16x8 af = *(const bf16x8*)(ldsb + A0 + kt * 64); \
      az0 = __builtin_amdgcn_mfma_f32_16x16x32_bf16(af, wzr[0][kt], az0, 0, 0, 0); \
      az1 = __builtin_amdgcn_mfma_f32_16x16x32_bf16(af, wzr[1][kt], az1, 0, 0, 0); \
      ar0 = __builtin_amdgcn_mfma_f32_16x16x32_bf16(af, wzr[2][kt], ar0, 0, 0, 0); \
      ar1 = __builtin_amdgcn_mfma_f32_16x16x32_bf16(af, wzr[3][kt], ar1, 0, 0, 0); \
    } \
    float zv00=0.f, zv10=0.f, zv01=0.f, zv11=0.f; \
    if (lk == 0){ \
      zv00 = sigmoidf_(az0[0] + gz00); zv10 = sigmoidf_(az1[0] + gz10); \
      zv01 = sigmoidf_(az0[1] + gz01); zv11 = sigmoidf_(az1[1] + gz11); \
      float rv00 = sigmoidf_(ar0[0] + gr00), rv10 = sigmoidf_(ar1[0] + gr10); \
      float rv01 = sigmoidf_(ar0[1] + gr01), rv11 = sigmoidf_(ar1[1] + gr11); \
      *(short*)(ldsb + 2048 + oA00) = f2bf(rv00 * h00); \
      *(short*)(ldsb + 2048 + oA10) = f2bf(rv10 * h10); \
      *(short*)(ldsb + 2048 + oA01) = f2bf(rv01 * h01); \
      *(short*)(ldsb + 2048 + oA11) = f2bf(rv11 * h11); \
    } \
    bar_lds(); \
    f32x4 an0 = Z4, an1 = Z4; \
    _Pragma("unroll") \
    for (int kt = 0; kt < 8; kt++){ \
      bf16x8 af = *(const bf16x8*)(ldsb + A0 + kt * 64 + 2048); \
      an0 = __builtin_amdgcn_mfma_f32_16x16x32_bf16(af, wn[0][kt], an0, 0, 0, 0); \
      an1 = __builtin_amdgcn_mfma_f32_16x16x32_bf16(af, wn[1][kt], an1, 0, 0, 0); \
    } \
    if (lk == 0){ \
      float nv00 = tanhf_(an0[0] + gn00), nv10 = tanhf_(an1[0] + gn10); \
      float nv01 = tanhf_(an0[1] + gn01), nv11 = tanhf_(an1[1] + gn11); \
      h00 = (1.f - zv00) * nv00 + zv00 * h00; \
      h10 = (1.f - zv10) * nv10 + zv10 * h10; \
      h01 = (1.f - zv01) * nv01 + zv01 * h01; \
      h11 = (1.f - zv11) * nv11 + zv11 * h11; \
      *(short*)(ldsb + oA00) = f2bf(h00); \
      *(short*)(ldsb + oA10) = f2bf(h10); \
      *(short*)(ldsb + oA01) = f2bf(h01); \
      *(short*)(ldsb + oA11) = f2bf(h11); \
      size_t ob = ((size_t)r0 * S_ + (T)) * H_; \
      if (OUT_BF16){ \
        ((short*)outp)[ob + col0]                 = f2bf(h00); \
        ((short*)outp)[ob + col1]                 = f2bf(h10); \
        ((short*)outp)[ob + (size_t)S_*H_ + col0] = f2bf(h01); \
        ((short*)outp)[ob + (size_t)S_*H_ + col1] = f2bf(h11); \
      } else { \
        ((float*)outp)[ob + col0]                 = h00; \
        ((float*)outp)[ob + col1]                 = h10; \
        ((float*)outp)[ob + (size_t)S_*H_ + col0] = h01; \
        ((float*)outp)[ob + (size_t)S_*H_ + col1] = h11; \
      } \
    } \
    bar_lds(); \
  } while (0)

#pragma unroll 1
  for (int t = 0; t < S_; t += 2){
    STEP(t, rgA0, rgB0);
    STEP(t + 1, rgA1, rgB1);
  }
#undef STEP

  if (lk == 0){
    finals[(size_t)r0 * H_ + col0]       = h00;
    finals[(size_t)r0 * H_ + col1]       = h10;
    finals[(size_t)(r0 + 1) * H_ + col0] = h01;
    finals[(size_t)(r0 + 1) * H_ + col1] = h11;
  }
}

// ---------------- launcher ----------------------------------------------------
extern "C" void kernel_launch(void* const* d_in, const int* in_sizes, int n_in,
                              void* d_out, int out_size, void* d_ws, size_t ws_size,
                              hipStream_t stream)
{
  (void)in_sizes; (void)n_in; (void)out_size; (void)ws_size;
  const float* x    = (const float*)d_in[0];
  const float* W_in = (const float*)d_in[1];
  const float* b_in = (const float*)d_in[2];
  const float* Wz   = (const float*)d_in[3];
  const float* bz   = (const float*)d_in[4];
  const float* Wr   = (const float*)d_in[5];
  const float* br   = (const float*)d_in[6];
  const float* Wn   = (const float*)d_in[7];
  const float* bn   = (const float*)d_in[8];
  float* out = (float*)d_out;

  char* ws = (char*)d_ws;
  short* Gbuf  = (short*)(ws + 0);            // [65536][768] bf16 (96MB)
  short* GpA   = (short*)(ws + 100663296);    // chunks*8 bf16 (64MB)
  short* GpB   = (short*)(ws + 167772160);    // chunks*4 bf16 (32MB)
  float* WcT   = (float*)(ws + 201326592);    // [128][768] fp32 tmp
  float* bc    = (float*)(ws + 201719808);    // [768]
  float* bcat1 = (float*)(ws + 201722880);    // [768]
  short* WCF   = (short*)(ws + 201725952);    // Wc frags (NT=48,KT=4)
  short* W1TF  = (short*)(ws + 201922560);    // layer1 top frags (NT=48,KT=8)
  short* WZR0  = (short*)(ws + 202315776);    // layer0 zr bottom frags
  short* WN0   = (short*)(ws + 202577920);    // layer0 n bottom frags
  short* WZR1  = (short*)(ws + 202708992);
  short* WN1   = (short*)(ws + 202971136);
  short* pipe  = (short*)(ws + 203102208);    // h0 sequence bf16 [b][t][256] (32MB)

  prep_compute<<<390, 256, 0, stream>>>(W_in, b_in, Wz, bz, Wr, br, Wn, bn, WcT, bc, bcat1);
  pack_wc <<<384, 256, 0, stream>>>(WCF, WcT);
  pack_top<<<768, 256, 0, stream>>>(W1TF, Wz, Wr, Wn);
  pack_zr <<<512, 256, 0, stream>>>(WZR0, Wz, Wr, 0);
  pack_n  <<<256, 256, 0, stream>>>(WN0, Wn, 0);
  pack_zr <<<512, 256, 0, stream>>>(WZR1, Wz, Wr, 1);
  pack_n  <<<256, 256, 0, stream>>>(WN1, Wn, 1);

  // G0 = x @ Wc + bc -> Gbuf ; repack -> GpA/GpB
  gemm_kernel<false, 4><<<dim3(1024, 6), 256, 0, stream>>>(x, WCF, bc, Gbuf);
  repack<<<16384, 256, 0, stream>>>((const unsigned short*)Gbuf, GpA, GpB);
  // layer 0 recurrence -> h0 pipe (bf16) + h_final[0]
  recur_kernel<true><<<NB_, 512, 0, stream>>>(GpA, GpB, WZR0, WN0, pipe, out + 16777216);
  // P1 = h0 @ W1_top + b1 -> Gbuf ; repack
  gemm_kernel<true, 8><<<dim3(1024, 6), 256, 0, stream>>>(pipe, W1TF, bcat1, Gbuf);
  repack<<<16384, 256, 0, stream>>>((const unsigned short*)Gbuf, GpA, GpB);
  // layer 1 recurrence -> outputs (fp32) + h_final[1]
  recur_kernel<false><<<NB_, 512, 0, stream>>>(GpA, GpB, WZR1, WN1, out, out + 16777216 + 32768);
}

// Round 4
// 2528.296 us; speedup vs baseline: 1.9076x; 1.0024x over previous
//
#include <hip/hip_runtime.h>
#include <stdint.h>

#define B_ 128
#define S_ 512
#define I_ 128
#define H_ 256

#define R_  2          // batch rows per recurrent block
#define NB_ (B_ / R_)  // 64 recurrent blocks

typedef short bf16x8 __attribute__((ext_vector_type(8)));
typedef short bf16x4 __attribute__((ext_vector_type(4)));
typedef float f32x4  __attribute__((ext_vector_type(4)));

__device__ __forceinline__ short f2bf(float f){
  unsigned u = __float_as_uint(f);
  u = (u + 0x7FFFu + ((u >> 16) & 1u)) >> 16;
  return (short)u;
}
__device__ __forceinline__ float bf2f(unsigned short u){
  return __uint_as_float(((unsigned)u) << 16);
}
__device__ __forceinline__ float sigmoidf_(float x){
  float e = __expf(-x);
  return __fdividef(1.f, 1.f + e);
}
__device__ __forceinline__ float tanhf_(float x){
  x = fminf(fmaxf(x, -10.f), 10.f);
  float e = __expf(2.f * x);
  return __fdividef(e - 1.f, e + 1.f);
}
// raw barrier: order LDS ops, do NOT drain vmcnt (keeps global prefetch in flight)
__device__ __forceinline__ void bar_lds(){
  asm volatile("s_waitcnt lgkmcnt(0)" ::: "memory");
  __builtin_amdgcn_s_barrier();
}

// ---------------- prep: combined input weights Wc = W_in @ Wg0_top, biases ----
__global__ __launch_bounds__(256) void prep_compute(
    const float* __restrict__ W_in, const float* __restrict__ b_in,
    const float* __restrict__ Wz, const float* __restrict__ bz,
    const float* __restrict__ Wr, const float* __restrict__ br,
    const float* __restrict__ Wn, const float* __restrict__ bn,
    float* __restrict__ WcT, float* __restrict__ bc, float* __restrict__ bcat1)
{
  int id = blockIdx.x * 256 + threadIdx.x;
  if (id < 98304){                       // Wc[i][gcol] = sum_j W_in[i][j]*Wg[0][j][n]
    int i = id / 768, gcol = id % 768;
    int g = gcol >> 8, n = gcol & 255;
    const float* Wg = (g == 0) ? Wz : (g == 1) ? Wr : Wn;
    float s = 0.f;
    for (int j = 0; j < 256; j++) s += W_in[i * 256 + j] * Wg[j * 256 + n];
    WcT[i * 768 + gcol] = s;
  } else if (id < 99072){                // bc[gcol] = b_in @ Wg0_top + bg0
    int gcol = id - 98304;
    int g = gcol >> 8, n = gcol & 255;
    const float* Wg = (g == 0) ? Wz : (g == 1) ? Wr : Wn;
    const float* bg = (g == 0) ? bz : (g == 1) ? br : bn;
    float s = 0.f;
    for (int j = 0; j < 256; j++) s += b_in[j] * Wg[j * 256 + n];
    bc[gcol] = s + bg[n];
  } else if (id < 99840){                // bcat1[gcol] = bg[1][n]
    int gcol = id - 99072;
    int g = gcol >> 8, n = gcol & 255;
    const float* bg = (g == 0) ? bz : (g == 1) ? br : bn;
    bcat1[gcol] = bg[256 + n];
  }
}

// ---------------- fragment packing -------------------------------------------
// B-frag layout (mfma_f32_16x16x32_bf16): lane l, elem j holds
//   B[kt*32 + (l>>4)*8 + j][nt*16 + (l&15)], stored dst[(((nt*KT+kt)*64+l)*8+j)]

__global__ __launch_bounds__(256) void pack_wc(short* __restrict__ dst, const float* __restrict__ WcT)
{
  int id = blockIdx.x * 256 + threadIdx.x;           // 98304 = 48nt * 4kt * 64 * 8
  int j = id & 7, l = (id >> 3) & 63, kt = (id >> 9) & 3, nt = id >> 11;
  int k = kt * 32 + (l >> 4) * 8 + j;
  int gcol = nt * 16 + (l & 15);
  dst[id] = f2bf(WcT[k * 768 + gcol]);
}

__global__ __launch_bounds__(256) void pack_top(short* __restrict__ dst,
    const float* __restrict__ Wz, const float* __restrict__ Wr, const float* __restrict__ Wn)
{
  int id = blockIdx.x * 256 + threadIdx.x;           // 196608 = 48nt * 8kt * 64 * 8
  int j = id & 7, l = (id >> 3) & 63, kt = (id >> 9) & 7, nt = id >> 12;
  int k = kt * 32 + (l >> 4) * 8 + j;                // 0..255  (layer-1 top half)
  int gcol = nt * 16 + (l & 15);
  int g = gcol >> 8, n = gcol & 255;
  const float* W = (g == 0) ? Wz : (g == 1) ? Wr : Wn;
  dst[id] = f2bf(W[(size_t)(512 + k) * 256 + n]);
}

__global__ __launch_bounds__(256) void pack_zr(short* __restrict__ dst,
    const float* __restrict__ Wz, const float* __restrict__ Wr, int layer)
{
  int id = blockIdx.x * 256 + threadIdx.x;           // 131072 = 32nt * 8kt * 64 * 8
  int j = id & 7, l = (id >> 3) & 63, kt = (id >> 9) & 7, nt = id >> 12;
  int k = kt * 32 + (l >> 4) * 8 + j;                // bottom half (h part)
  int n = (nt & 15) * 16 + (l & 15);
  const float* W = (nt < 16) ? Wz : Wr;
  dst[id] = f2bf(W[((size_t)layer * 512 + 256 + k) * 256 + n]);
}

__global__ __launch_bounds__(256) void pack_n(short* __restrict__ dst,
    const float* __restrict__ Wn, int layer)
{
  int id = blockIdx.x * 256 + threadIdx.x;           // 65536 = 16nt * 8kt * 64 * 8
  int j = id & 7, l = (id >> 3) & 63, kt = (id >> 9) & 7, nt = id >> 12;
  int k = kt * 32 + (l >> 4) * 8 + j;
  int n = nt * 16 + (l & 15);
  dst[id] = f2bf(Wn[((size_t)layer * 512 + 256 + k) * 256 + n]);
}

// ---------------- big parallel GEMM: C[M,768] = A[M,K] @ Bfrags + bias --------
// output bf16 [mrow][768]
template<bool ABF16, int KT>
__global__ __launch_bounds__(256) void gemm_kernel(
    const void* __restrict__ Ap, const short* __restrict__ BF,
    const float* __restrict__ bias, short* __restrict__ C)
{
  const int tid = threadIdx.x, w = tid >> 6, l = tid & 63;
  const int m0 = blockIdx.x * 64 + w * 16;
  const int nb = blockIdx.y;
  const int K = KT * 32;
  f32x4 zero4 = {0.f, 0.f, 0.f, 0.f};
  f32x4 acc[8];
#pragma unroll
  for (int nt = 0; nt < 8; nt++) acc[nt] = zero4;

#pragma unroll
  for (int kt = 0; kt < KT; kt++){
    bf16x8 af;
    if (ABF16){
      af = *(const bf16x8*)((const short*)Ap + (size_t)(m0 + (l & 15)) * K + kt * 32 + (l >> 4) * 8);
    } else {
      const float* A = (const float*)Ap + (size_t)(m0 + (l & 15)) * K + kt * 32 + (l >> 4) * 8;
      f32x4 a0 = *(const f32x4*)A;
      f32x4 a1 = *(const f32x4*)(A + 4);
      af[0] = f2bf(a0[0]); af[1] = f2bf(a0[1]); af[2] = f2bf(a0[2]); af[3] = f2bf(a0[3]);
      af[4] = f2bf(a1[0]); af[5] = f2bf(a1[1]); af[6] = f2bf(a1[2]); af[7] = f2bf(a1[3]);
    }
#pragma unroll
    for (int nt = 0; nt < 8; nt++){
      bf16x8 bf = *(const bf16x8*)(BF + (size_t)(((nb * 8 + nt) * KT + kt) * 64 + l) * 8);
      acc[nt] = __builtin_amdgcn_mfma_f32_16x16x32_bf16(af, bf, acc[nt], 0, 0, 0);
    }
  }
#pragma unroll
  for (int nt = 0; nt < 8; nt++){
    int col = nb * 128 + nt * 16 + (l & 15);
    float bv = bias[col];
#pragma unroll
    for (int rr = 0; rr < 4; rr++){
      int mrow = m0 + (l >> 4) * 4 + rr;
      C[(size_t)mrow * 768 + col] = f2bf(acc[nt][rr] + bv);
    }
  }
}

// ---------------- repack Gbuf -> per-thread chunks ---------------------------
// chunk id = blk*65536 + t*128 + w*16 + cix ; values v[rr*6+i*3+gate]
// GpA[id*8+0..7] = v0..7 ; GpB[id*4+0..3] = v8..11
__global__ __launch_bounds__(256) void repack(const unsigned short* __restrict__ Gbuf,
                                              short* __restrict__ GpA, short* __restrict__ GpB)
{
  int id = blockIdx.x * 256 + threadIdx.x;   // 4,194,304 total
  int cix = id & 15, wv = (id >> 4) & 7, t = (id >> 7) & 511, blk = id >> 16;
  short v[12];
#pragma unroll
  for (int rr = 0; rr < 2; rr++)
#pragma unroll
    for (int i = 0; i < 2; i++)
#pragma unroll
      for (int g = 0; g < 3; g++)
        v[rr * 6 + i * 3 + g] =
          (short)Gbuf[((size_t)(2 * blk + rr) * 512 + t) * 768 + g * 256 + i * 128 + wv * 16 + cix];
  bf16x8 a; bf16x4 b;
#pragma unroll
  for (int j = 0; j < 8; j++) a[j] = v[j];
#pragma unroll
  for (int j = 0; j < 4; j++) b[j] = v[8 + j];
  *(bf16x8*)(GpA + (size_t)id * 8) = a;
  *(bf16x4*)(GpB + (size_t)id * 4) = b;
}

// ---------------- persistent recurrent core ----------------------------------
// 64 blocks x 512 threads (8 waves). __launch_bounds__(512,1): min 1 BLOCK/CU
// -> 2 waves/SIMD -> 256-VGPR cap. Weight frags (192 VGPR) + acc (24) + G ring
// (12) must be fully register-resident: NO SPILLS is the whole point.
// Block = 2 batch rows. LDS 4KB:
//   hA rows 0,1 @ 0/512 ; zero region @1024..1535 ; rA rows @2048/2560 ;
//   (rA-read zero = hA-zero + 2048 = 3072..3583, also zeroed)
// swizzle: (row,col) -> row*512 + (((col>>3)^row)<<4) + (col&7)*2
// A-frag read: lane(cix,lk): cix<2 -> cix*512 + ((kt*4+(lk^cix))<<4) ; else 1024 (bcast zero)
template<bool OUT_BF16>
__global__ __launch_bounds__(512, 1) void recur_kernel(
    const short* __restrict__ GpA, const short* __restrict__ GpB,
    const short* __restrict__ WzrF, const short* __restrict__ WnF,
    void* __restrict__ outp, float* __restrict__ finals)
{
  __shared__ __align__(16) char ldsb[4096];

  const int tid = threadIdx.x;
  const int w = tid >> 6, l = tid & 63;
  const int cix = l & 15, lk = l >> 4;
  const int r0 = blockIdx.x * R_;
  const int chunkBase = blockIdx.x * 65536 + w * 16 + cix;

  // weight fragments (192 VGPR)
  bf16x8 wzr[4][8];
  bf16x8 wn[2][8];
#pragma unroll
  for (int i = 0; i < 4; i++)
#pragma unroll
    for (int kt = 0; kt < 8; kt++)
      wzr[i][kt] = *(const bf16x8*)(WzrF + (size_t)((((w + 8 * i) * 8 + kt) * 64 + l) * 8));
#pragma unroll
  for (int i = 0; i < 2; i++)
#pragma unroll
    for (int kt = 0; kt < 8; kt++)
      wn[i][kt] = *(const bf16x8*)(WnF + (size_t)((((w + 8 * i) * 8 + kt) * 64 + l) * 8));

  // zero all of LDS (h0 = 0, zero-broadcast regions)
  *(uint64_t*)(ldsb + tid * 8) = 0ull;
  __syncthreads();

  // A-frag read base (one reg; per-kt offsets are immediates)
  const int A0 = (cix < 2) ? cix * 512 + ((lk ^ cix) << 4) : 1024;
  // LDS write offsets (row,col) for lk==0 lanes
  const int col0 = w * 16 + cix, col1 = col0 + 128;
  const int oA00 = col0 * 2;                    // row0, i0
  const int oA10 = col1 * 2;                    // row0, i1
  const int oA01 = 512 + ((col0 * 2) ^ 16);     // row1, i0
  const int oA11 = 512 + ((col1 * 2) ^ 16);     // row1, i1

  float h00 = 0.f, h10 = 0.f, h01 = 0.f, h11 = 0.f;  // h[i][rr]

  // G ring, depth 2
  bf16x8 rgA0{}, rgA1{};
  bf16x4 rgB0{}, rgB1{};
  if (lk == 0){
    rgA0 = *(const bf16x8*)(GpA + (size_t)chunkBase * 8);
    rgB0 = *(const bf16x4*)(GpB + (size_t)chunkBase * 4);
    rgA1 = *(const bf16x8*)(GpA + (size_t)(chunkBase + 128) * 8);
    rgB1 = *(const bf16x4*)(GpB + (size_t)(chunkBase + 128) * 4);
  }

  const f32x4 Z4 = {0.f, 0.f, 0.f, 0.f};

#define STEP(T, RGA, RGB) do { \
    float gz00=0.f,gz10=0.f,gz01=0.f,gz11=0.f; \
    float gr00=0.f,gr10=0.f,gr01=0.f,gr11=0.f; \
    float gn00=0.f,gn10=0.f,gn01=0.f,gn11=0.f; \
    if (lk == 0){ \
      gz00=bf2f((unsigned short)RGA[0]); gr00=bf2f((unsigned short)RGA[1]); gn00=bf2f((unsigned short)RGA[2]); \
      gz10=bf2f((unsigned short)RGA[3]); gr10=bf2f((unsigned short)RGA[4]); gn10=bf2f((unsigned short)RGA[5]); \
      gz01=bf2f((unsigned short)RGA[6]); gr01=bf2f((unsigned short)RGA[7]); \
      gn01=bf2f((unsigned short)RGB[0]); gz11=bf2f((unsigned short)RGB[1]); \
      gr11=bf2f((unsigned short)RGB[2]); gn11=bf2f((unsigned short)RGB[3]); \
      int tn = (T) + 2; if (tn >= S_) tn = (T); \
      size_t ch = (size_t)chunkBase + (size_t)tn * 128; \
      RGA = *(const bf16x8*)(GpA + ch * 8); \
      RGB = *(const bf16x4*)(GpB + ch * 4); \
    } \
    f32x4 az0 = Z4, az1 = Z4, ar0 = Z4, ar1 = Z4; \
    _Pragma("unroll") \
    for (int kt = 0; kt < 8; kt++){ \
      bf16x8 af = *(const bf16x8*)(ldsb + A0 + kt * 64); \
      az0 = __builtin_amdgcn_mfma_f32_16x16x32_bf16(af, wzr[0][kt], az0, 0, 0, 0); \
      az1 = __builtin_amdgcn_mfma_f32_16x16x32_bf16(af, wzr[1][kt], az1, 0, 0, 0); \
      ar0 = __builtin_amdgcn_mfma_f32_16x16x32_bf16(af, wzr[2][kt], ar0, 0, 0, 0); \
      ar1 = __builtin_amdgcn_mfma_f32_16x16x32_bf16(af, wzr[3][kt], ar1, 0, 0, 0); \
    } \
    float zv00=0.f, zv10=0.f, zv01=0.f, zv11=0.f; \
    if (lk == 0){ \
      zv00 = sigmoidf_(az0[0] + gz00); zv10 = sigmoidf_(az1[0] + gz10); \
      zv01 = sigmoidf_(az0[1] + gz01); zv11 = sigmoidf_(az1[1] + gz11); \
      float rv00 = sigmoidf_(ar0[0] + gr00), rv10 = sigmoidf_(ar1[0] + gr10); \
      float rv01 = sigmoidf_(ar0[1] + gr01), rv11 = sigmoidf_(ar1[1] + gr11); \
      *(short*)(ldsb + 2048 + oA00) = f2bf(rv00 * h00); \
      *(short*)(ldsb + 2048 + oA10) = f2bf(rv10 * h10); \
      *(short*)(ldsb + 2048 + oA01) = f2bf(rv01 * h01); \
      *(short*)(ldsb + 2048 + oA11) = f2bf(rv11 * h11); \
    } \
    bar_lds(); \
    f32x4 an0 = Z4, an1 = Z4; \
    _Pragma("unroll") \
    for (int kt = 0; kt < 8; kt++){ \
      bf16x8 af = *(const bf16x8*)(ldsb + A0 + kt * 64 + 2048); \
      an0 = __builtin_amdgcn_mfma_f32_16x16x32_bf16(af, wn[0][kt], an0, 0, 0, 0); \
      an1 = __builtin_amdgcn_mfma_f32_16x16x32_bf16(af, wn[1][kt], an1, 0, 0, 0); \
    } \
    if (lk == 0){ \
      float nv00 = tanhf_(an0[0] + gn00), nv10 = tanhf_(an1[0] + gn10); \
      float nv01 = tanhf_(an0[1] + gn01), nv11 = tanhf_(an1[1] + gn11); \
      h00 = (1.f - zv00) * nv00 + zv00 * h00; \
      h10 = (1.f - zv10) * nv10 + zv10 * h10; \
      h01 = (1.f - zv01) * nv01 + zv01 * h01; \
      h11 = (1.f - zv11) * nv11 + zv11 * h11; \
      *(short*)(ldsb + oA00) = f2bf(h00); \
      *(short*)(ldsb + oA10) = f2bf(h10); \
      *(short*)(ldsb + oA01) = f2bf(h01); \
      *(short*)(ldsb + oA11) = f2bf(h11); \
      size_t ob = ((size_t)r0 * S_ + (T)) * H_; \
      if (OUT_BF16){ \
        ((short*)outp)[ob + col0]                 = f2bf(h00); \
        ((short*)outp)[ob + col1]                 = f2bf(h10); \
        ((short*)outp)[ob + (size_t)S_*H_ + col0] = f2bf(h01); \
        ((short*)outp)[ob + (size_t)S_*H_ + col1] = f2bf(h11); \
      } else { \
        ((float*)outp)[ob + col0]                 = h00; \
        ((float*)outp)[ob + col1]                 = h10; \
        ((float*)outp)[ob + (size_t)S_*H_ + col0] = h01; \
        ((float*)outp)[ob + (size_t)S_*H_ + col1] = h11; \
      } \
    } \
    bar_lds(); \
  } while (0)

#pragma unroll 1
  for (int t = 0; t < S_; t += 2){
    STEP(t, rgA0, rgB0);
    STEP(t + 1, rgA1, rgB1);
  }
#undef STEP

  if (lk == 0){
    finals[(size_t)r0 * H_ + col0]       = h00;
    finals[(size_t)r0 * H_ + col1]       = h10;
    finals[(size_t)(r0 + 1) * H_ + col0] = h01;
    finals[(size_t)(r0 + 1) * H_ + col1] = h11;
  }
}

// ---------------- launcher ----------------------------------------------------
extern "C" void kernel_launch(void* const* d_in, const int* in_sizes, int n_in,
                              void* d_out, int out_size, void* d_ws, size_t ws_size,
                              hipStream_t stream)
{
  (void)in_sizes; (void)n_in; (void)out_size; (void)ws_size;
  const float* x    = (const float*)d_in[0];
  const float* W_in = (const float*)d_in[1];
  const float* b_in = (const float*)d_in[2];
  const float* Wz   = (const float*)d_in[3];
  const float* bz   = (const float*)d_in[4];
  const float* Wr   = (const float*)d_in[5];
  const float* br   = (const float*)d_in[6];
  const float* Wn   = (const float*)d_in[7];
  const float* bn   = (const float*)d_in[8];
  float* out = (float*)d_out;

  char* ws = (char*)d_ws;
  short* Gbuf  = (short*)(ws + 0);            // [65536][768] bf16 (96MB)
  short* GpA   = (short*)(ws + 100663296);    // chunks*8 bf16 (64MB)
  short* GpB   = (short*)(ws + 167772160);    // chunks*4 bf16 (32MB)
  float* WcT   = (float*)(ws + 201326592);    // [128][768] fp32 tmp
  float* bc    = (float*)(ws + 201719808);    // [768]
  float* bcat1 = (float*)(ws + 201722880);    // [768]
  short* WCF   = (short*)(ws + 201725952);    // Wc frags (NT=48,KT=4)
  short* W1TF  = (short*)(ws + 201922560);    // layer1 top frags (NT=48,KT=8)
  short* WZR0  = (short*)(ws + 202315776);    // layer0 zr bottom frags
  short* WN0   = (short*)(ws + 202577920);    // layer0 n bottom frags
  short* WZR1  = (short*)(ws + 202708992);
  short* WN1   = (short*)(ws + 202971136);
  short* pipe  = (short*)(ws + 203102208);    // h0 sequence bf16 [b][t][256] (32MB)

  prep_compute<<<390, 256, 0, stream>>>(W_in, b_in, Wz, bz, Wr, br, Wn, bn, WcT, bc, bcat1);
  pack_wc <<<384, 256, 0, stream>>>(WCF, WcT);
  pack_top<<<768, 256, 0, stream>>>(W1TF, Wz, Wr, Wn);
  pack_zr <<<512, 256, 0, stream>>>(WZR0, Wz, Wr, 0);
  pack_n  <<<256, 256, 0, stream>>>(WN0, Wn, 0);
  pack_zr <<<512, 256, 0, stream>>>(WZR1, Wz, Wr, 1);
  pack_n  <<<256, 256, 0, stream>>>(WN1, Wn, 1);

  // G0 = x @ Wc + bc -> Gbuf ; repack -> GpA/GpB
  gemm_kernel<false, 4><<<dim3(1024, 6), 256, 0, stream>>>(x, WCF, bc, Gbuf);
  repack<<<16384, 256, 0, stream>>>((const unsigned short*)Gbuf, GpA, GpB);
  // layer 0 recurrence -> h0 pipe (bf16) + h_final[0]
  recur_kernel<true><<<NB_, 512, 0, stream>>>(GpA, GpB, WZR0, WN0, pipe, out + 16777216);
  // P1 = h0 @ W1_top + b1 -> Gbuf ; repack
  gemm_kernel<true, 8><<<dim3(1024, 6), 256, 0, stream>>>(pipe, W1TF, bcat1, Gbuf);
  repack<<<16384, 256, 0, stream>>>((const unsigned short*)Gbuf, GpA, GpB);
  // layer 1 recurrence -> outputs (fp32) + h_final[1]
  recur_kernel<false><<<NB_, 512, 0, stream>>>(GpA, GpB, WZR1, WN1, out, out + 16777216 + 32768);
}

// Round 7
// 2321.641 us; speedup vs baseline: 2.0774x; 1.0890x over previous
//
#include <hip/hip_runtime.h>
#include <stdint.h>

#define B_ 128
#define S_ 512
#define I_ 128
#define H_ 256

#define R_  2          // batch rows per recurrent block
#define NB_ (B_ / R_)  // 64 recurrent blocks

typedef short bf16x8 __attribute__((ext_vector_type(8)));
typedef short bf16x4 __attribute__((ext_vector_type(4)));
typedef float f32x4  __attribute__((ext_vector_type(4)));

__device__ __forceinline__ short f2bf(float f){
  unsigned u = __float_as_uint(f);
  u = (u + 0x7FFFu + ((u >> 16) & 1u)) >> 16;
  return (short)u;
}
__device__ __forceinline__ float bf2f(unsigned short u){
  return __uint_as_float(((unsigned)u) << 16);
}
__device__ __forceinline__ float sigmoidf_(float x){
  float e = __expf(-x);
  return __fdividef(1.f, 1.f + e);
}
__device__ __forceinline__ float tanhf_(float x){
  x = fminf(fmaxf(x, -10.f), 10.f);
  float e = __expf(2.f * x);
  return __fdividef(e - 1.f, e + 1.f);
}
// raw barrier: order LDS ops, do NOT drain vmcnt (keeps global prefetch in flight)
__device__ __forceinline__ void bar_lds(){
  asm volatile("s_waitcnt lgkmcnt(0)" ::: "memory");
  __builtin_amdgcn_s_barrier();
}

// ---------------- prep: combined input weights Wc = W_in @ Wg0_top, biases ----
__global__ __launch_bounds__(256) void prep_compute(
    const float* __restrict__ W_in, const float* __restrict__ b_in,
    const float* __restrict__ Wz, const float* __restrict__ bz,
    const float* __restrict__ Wr, const float* __restrict__ br,
    const float* __restrict__ Wn, const float* __restrict__ bn,
    float* __restrict__ WcT, float* __restrict__ bc, float* __restrict__ bcat1)
{
  int id = blockIdx.x * 256 + threadIdx.x;
  if (id < 98304){                       // Wc[i][gcol] = sum_j W_in[i][j]*Wg[0][j][n]
    int i = id / 768, gcol = id % 768;
    int g = gcol >> 8, n = gcol & 255;
    const float* Wg = (g == 0) ? Wz : (g == 1) ? Wr : Wn;
    float s = 0.f;
    for (int j = 0; j < 256; j++) s += W_in[i * 256 + j] * Wg[j * 256 + n];
    WcT[i * 768 + gcol] = s;
  } else if (id < 99072){                // bc[gcol] = b_in @ Wg0_top + bg0
    int gcol = id - 98304;
    int g = gcol >> 8, n = gcol & 255;
    const float* Wg = (g == 0) ? Wz : (g == 1) ? Wr : Wn;
    const float* bg = (g == 0) ? bz : (g == 1) ? br : bn;
    float s = 0.f;
    for (int j = 0; j < 256; j++) s += b_in[j] * Wg[j * 256 + n];
    bc[gcol] = s + bg[n];
  } else if (id < 99840){                // bcat1[gcol] = bg[1][n]
    int gcol = id - 99072;
    int g = gcol >> 8, n = gcol & 255;
    const float* bg = (g == 0) ? bz : (g == 1) ? br : bn;
    bcat1[gcol] = bg[256 + n];
  }
}

// ---------------- fragment packing -------------------------------------------
// B-frag layout (mfma_f32_16x16x32_bf16): lane l, elem j holds
//   B[kt*32 + (l>>4)*8 + j][nt*16 + (l&15)], stored dst[(((nt*KT+kt)*64+l)*8+j)]

__global__ __launch_bounds__(256) void pack_wc(short* __restrict__ dst, const float* __restrict__ WcT)
{
  int id = blockIdx.x * 256 + threadIdx.x;           // 98304 = 48nt * 4kt * 64 * 8
  int j = id & 7, l = (id >> 3) & 63, kt = (id >> 9) & 3, nt = id >> 11;
  int k = kt * 32 + (l >> 4) * 8 + j;
  int gcol = nt * 16 + (l & 15);
  dst[id] = f2bf(WcT[k * 768 + gcol]);
}

__global__ __launch_bounds__(256) void pack_top(short* __restrict__ dst,
    const float* __restrict__ Wz, const float* __restrict__ Wr, const float* __restrict__ Wn)
{
  int id = blockIdx.x * 256 + threadIdx.x;           // 196608 = 48nt * 8kt * 64 * 8
  int j = id & 7, l = (id >> 3) & 63, kt = (id >> 9) & 7, nt = id >> 12;
  int k = kt * 32 + (l >> 4) * 8 + j;                // 0..255  (layer-1 top half)
  int gcol = nt * 16 + (l & 15);
  int g = gcol >> 8, n = gcol & 255;
  const float* W = (g == 0) ? Wz : (g == 1) ? Wr : Wn;
  dst[id] = f2bf(W[(size_t)(512 + k) * 256 + n]);
}

__global__ __launch_bounds__(256) void pack_zr(short* __restrict__ dst,
    const float* __restrict__ Wz, const float* __restrict__ Wr, int layer)
{
  int id = blockIdx.x * 256 + threadIdx.x;           // 131072 = 32nt * 8kt * 64 * 8
  int j = id & 7, l = (id >> 3) & 63, kt = (id >> 9) & 7, nt = id >> 12;
  int k = kt * 32 + (l >> 4) * 8 + j;                // bottom half (h part)
  int n = (nt & 15) * 16 + (l & 15);
  const float* W = (nt < 16) ? Wz : Wr;
  dst[id] = f2bf(W[((size_t)layer * 512 + 256 + k) * 256 + n]);
}

__global__ __launch_bounds__(256) void pack_n(short* __restrict__ dst,
    const float* __restrict__ Wn, int layer)
{
  int id = blockIdx.x * 256 + threadIdx.x;           // 65536 = 16nt * 8kt * 64 * 8
  int j = id & 7, l = (id >> 3) & 63, kt = (id >> 9) & 7, nt = id >> 12;
  int k = kt * 32 + (l >> 4) * 8 + j;
  int n = nt * 16 + (l & 15);
  dst[id] = f2bf(Wn[((size_t)layer * 512 + 256 + k) * 256 + n]);
}

// ---------------- big parallel GEMM: C[M,768] = A[M,K] @ Bfrags + bias --------
// output bf16 [mrow][768]
template<bool ABF16, int KT>
__global__ __launch_bounds__(256) void gemm_kernel(
    const void* __restrict__ Ap, const short* __restrict__ BF,
    const float* __restrict__ bias, short* __restrict__ C)
{
  const int tid = threadIdx.x, w = tid >> 6, l = tid & 63;
  const int m0 = blockIdx.x * 64 + w * 16;
  const int nb = blockIdx.y;
  const int K = KT * 32;
  f32x4 zero4 = {0.f, 0.f, 0.f, 0.f};
  f32x4 acc[8];
#pragma unroll
  for (int nt = 0; nt < 8; nt++) acc[nt] = zero4;

#pragma unroll
  for (int kt = 0; kt < KT; kt++){
    bf16x8 af;
    if (ABF16){
      af = *(const bf16x8*)((const short*)Ap + (size_t)(m0 + (l & 15)) * K + kt * 32 + (l >> 4) * 8);
    } else {
      const float* A = (const float*)Ap + (size_t)(m0 + (l & 15)) * K + kt * 32 + (l >> 4) * 8;
      f32x4 a0 = *(const f32x4*)A;
      f32x4 a1 = *(const f32x4*)(A + 4);
      af[0] = f2bf(a0[0]); af[1] = f2bf(a0[1]); af[2] = f2bf(a0[2]); af[3] = f2bf(a0[3]);
      af[4] = f2bf(a1[0]); af[5] = f2bf(a1[1]); af[6] = f2bf(a1[2]); af[7] = f2bf(a1[3]);
    }
#pragma unroll
    for (int nt = 0; nt < 8; nt++){
      bf16x8 bf = *(const bf16x8*)(BF + (size_t)(((nb * 8 + nt) * KT + kt) * 64 + l) * 8);
      acc[nt] = __builtin_amdgcn_mfma_f32_16x16x32_bf16(af, bf, acc[nt], 0, 0, 0);
    }
  }
#pragma unroll
  for (int nt = 0; nt < 8; nt++){
    int col = nb * 128 + nt * 16 + (l & 15);
    float bv = bias[col];
#pragma unroll
    for (int rr = 0; rr < 4; rr++){
      int mrow = m0 + (l >> 4) * 4 + rr;
      C[(size_t)mrow * 768 + col] = f2bf(acc[nt][rr] + bv);
    }
  }
}

// ---------------- repack Gbuf -> per-thread chunks ---------------------------
// chunk id = blk*65536 + t*128 + w*16 + cix ; values v[rr*6+i*3+gate]
// GpA[id*8+0..7] = v0..7 ; GpB[id*4+0..3] = v8..11
__global__ __launch_bounds__(256) void repack(const unsigned short* __restrict__ Gbuf,
                                              short* __restrict__ GpA, short* __restrict__ GpB)
{
  int id = blockIdx.x * 256 + threadIdx.x;   // 4,194,304 total
  int cix = id & 15, wv = (id >> 4) & 7, t = (id >> 7) & 511, blk = id >> 16;
  short v[12];
#pragma unroll
  for (int rr = 0; rr < 2; rr++)
#pragma unroll
    for (int i = 0; i < 2; i++)
#pragma unroll
      for (int g = 0; g < 3; g++)
        v[rr * 6 + i * 3 + g] =
          (short)Gbuf[((size_t)(2 * blk + rr) * 512 + t) * 768 + g * 256 + i * 128 + wv * 16 + cix];
  bf16x8 a; bf16x4 b;
#pragma unroll
  for (int j = 0; j < 8; j++) a[j] = v[j];
#pragma unroll
  for (int j = 0; j < 4; j++) b[j] = v[8 + j];
  *(bf16x8*)(GpA + (size_t)id * 8) = a;
  *(bf16x4*)(GpB + (size_t)id * 4) = b;
}

// ---------------- persistent recurrent core ----------------------------------
// 64 blocks x 512 threads (8 waves, 2/SIMD). Register-pressure fix this round:
// wn fragments (64 regs/lane) move to LDS (128KB block copy of Wn, written once,
// read per step as contiguous per-lane ds_read_b128 = conflict-free). Register
// demand ~200/wave -> fits the 256/wave budget with no spills/copies.
// wzr (128 regs) stays register-resident; MFMA via builtin (hazards handled).
// Block = 2 batch rows. LDS: state 4KB + wnL 128KB = 132KB (1 block/CU, which
// is all we use anyway: 64 blocks on 256 CUs).
// state LDS: hA rows 0,1 @ 0/512 ; zero region @1024..1535 ; rA rows @2048/2560
// swizzle: (row,col) -> row*512 + (((col>>3)^row)<<4) + (col&7)*2
// A-frag read: lane(cix,lk): cix<2 -> cix*512 + ((kt*4+(lk^cix))<<4) ; else 1024 (bcast zero)
template<bool OUT_BF16>
__global__ __launch_bounds__(512, 1) void recur_kernel(
    const short* __restrict__ GpA, const short* __restrict__ GpB,
    const short* __restrict__ WzrF, const short* __restrict__ WnF,
    void* __restrict__ outp, float* __restrict__ finals)
{
  __shared__ __align__(16) char ldsb[4096];
  __shared__ __align__(16) short wnL[65536];   // 128KB: [(w*2+i)*8+kt][lane][8]

  const int tid = threadIdx.x;
  const int w = tid >> 6, l = tid & 63;
  const int cix = l & 15, lk = l >> 4;
  const int r0 = blockIdx.x * R_;
  const int chunkBase = blockIdx.x * 65536 + w * 16 + cix;

  // zero state LDS (h0 = 0, zero-broadcast regions)
  *(uint64_t*)(ldsb + tid * 8) = 0ull;

  // zr weight fragments stay in registers (128 regs/lane)
  bf16x8 wzr[4][8];
#pragma unroll
  for (int i = 0; i < 4; i++)
#pragma unroll
    for (int kt = 0; kt < 8; kt++)
      wzr[i][kt] = *(const bf16x8*)(WzrF + (size_t)((((w + 8 * i) * 8 + kt) * 64 + l) * 8));
  // n weight fragments -> LDS (written once; per-lane contiguous 16B)
#pragma unroll
  for (int i = 0; i < 2; i++)
#pragma unroll
    for (int kt = 0; kt < 8; kt++){
      bf16x8 v = *(const bf16x8*)(WnF + (size_t)((((w + 8 * i) * 8 + kt) * 64 + l) * 8));
      *(bf16x8*)(wnL + (size_t)(((w * 2 + i) * 8 + kt) * 64 + l) * 8) = v;
    }
  __syncthreads();

  // A-frag read base (one reg; per-kt offsets are immediates)
  const int A0 = (cix < 2) ? cix * 512 + ((lk ^ cix) << 4) : 1024;
  // wn LDS read bases (shorts): frag block = 64 lanes * 8 shorts = 512
  const short* wn0p = wnL + (size_t)(w * 2 + 0) * 8 * 512 + l * 8;
  const short* wn1p = wnL + (size_t)(w * 2 + 1) * 8 * 512 + l * 8;
  // LDS write offsets (row,col) for lk==0 lanes
  const int col0 = w * 16 + cix, col1 = col0 + 128;
  const int oA00 = col0 * 2;                    // row0, i0
  const int oA10 = col1 * 2;                    // row0, i1
  const int oA01 = 512 + ((col0 * 2) ^ 16);     // row1, i0
  const int oA11 = 512 + ((col1 * 2) ^ 16);     // row1, i1

  float h00 = 0.f, h10 = 0.f, h01 = 0.f, h11 = 0.f;  // h[i][rr]

  // G ring, depth 2
  bf16x8 rgA0{}, rgA1{};
  bf16x4 rgB0{}, rgB1{};
  if (lk == 0){
    rgA0 = *(const bf16x8*)(GpA + (size_t)chunkBase * 8);
    rgB0 = *(const bf16x4*)(GpB + (size_t)chunkBase * 4);
    rgA1 = *(const bf16x8*)(GpA + (size_t)(chunkBase + 128) * 8);
    rgB1 = *(const bf16x4*)(GpB + (size_t)(chunkBase + 128) * 4);
  }

  const f32x4 Z4 = {0.f, 0.f, 0.f, 0.f};

#define STEP(T, RGA, RGB) do { \
    float gz00=0.f,gz10=0.f,gz01=0.f,gz11=0.f; \
    float gr00=0.f,gr10=0.f,gr01=0.f,gr11=0.f; \
    float gn00=0.f,gn10=0.f,gn01=0.f,gn11=0.f; \
    if (lk == 0){ \
      gz00=bf2f((unsigned short)RGA[0]); gr00=bf2f((unsigned short)RGA[1]); gn00=bf2f((unsigned short)RGA[2]); \
      gz10=bf2f((unsigned short)RGA[3]); gr10=bf2f((unsigned short)RGA[4]); gn10=bf2f((unsigned short)RGA[5]); \
      gz01=bf2f((unsigned short)RGA[6]); gr01=bf2f((unsigned short)RGA[7]); \
      gn01=bf2f((unsigned short)RGB[0]); gz11=bf2f((unsigned short)RGB[1]); \
      gr11=bf2f((unsigned short)RGB[2]); gn11=bf2f((unsigned short)RGB[3]); \
      int tn = (T) + 2; if (tn >= S_) tn = (T); \
      size_t ch = (size_t)chunkBase + (size_t)tn * 128; \
      RGA = *(const bf16x8*)(GpA + ch * 8); \
      RGB = *(const bf16x4*)(GpB + ch * 4); \
    } \
    f32x4 az0 = Z4, az1 = Z4, ar0 = Z4, ar1 = Z4; \
    _Pragma("unroll") \
    for (int kt = 0; kt < 8; kt++){ \
      bf16x8 af = *(const bf16x8*)(ldsb + A0 + kt * 64); \
      az0 = __builtin_amdgcn_mfma_f32_16x16x32_bf16(af, wzr[0][kt], az0, 0, 0, 0); \
      az1 = __builtin_amdgcn_mfma_f32_16x16x32_bf16(af, wzr[1][kt], az1, 0, 0, 0); \
      ar0 = __builtin_amdgcn_mfma_f32_16x16x32_bf16(af, wzr[2][kt], ar0, 0, 0, 0); \
      ar1 = __builtin_amdgcn_mfma_f32_16x16x32_bf16(af, wzr[3][kt], ar1, 0, 0, 0); \
    } \
    float zv00=0.f, zv10=0.f, zv01=0.f, zv11=0.f; \
    if (lk == 0){ \
      zv00 = sigmoidf_(az0[0] + gz00); zv10 = sigmoidf_(az1[0] + gz10); \
      zv01 = sigmoidf_(az0[1] + gz01); zv11 = sigmoidf_(az1[1] + gz11); \
      float rv00 = sigmoidf_(ar0[0] + gr00), rv10 = sigmoidf_(ar1[0] + gr10); \
      float rv01 = sigmoidf_(ar0[1] + gr01), rv11 = sigmoidf_(ar1[1] + gr11); \
      *(short*)(ldsb + 2048 + oA00) = f2bf(rv00 * h00); \
      *(short*)(ldsb + 2048 + oA10) = f2bf(rv10 * h10); \
      *(short*)(ldsb + 2048 + oA01) = f2bf(rv01 * h01); \
      *(short*)(ldsb + 2048 + oA11) = f2bf(rv11 * h11); \
    } \
    bar_lds(); \
    f32x4 an0 = Z4, an1 = Z4; \
    _Pragma("unroll") \
    for (int kt = 0; kt < 8; kt++){ \
      bf16x8 af = *(const bf16x8*)(ldsb + A0 + kt * 64 + 2048); \
      bf16x8 w0 = *(const bf16x8*)(wn0p + kt * 512); \
      bf16x8 w1 = *(const bf16x8*)(wn1p + kt * 512); \
      an0 = __builtin_amdgcn_mfma_f32_16x16x32_bf16(af, w0, an0, 0, 0, 0); \
      an1 = __builtin_amdgcn_mfma_f32_16x16x32_bf16(af, w1, an1, 0, 0, 0); \
    } \
    if (lk == 0){ \
      float nv00 = tanhf_(an0[0] + gn00), nv10 = tanhf_(an1[0] + gn10); \
      float nv01 = tanhf_(an0[1] + gn01), nv11 = tanhf_(an1[1] + gn11); \
      h00 = (1.f - zv00) * nv00 + zv00 * h00; \
      h10 = (1.f - zv10) * nv10 + zv10 * h10; \
      h01 = (1.f - zv01) * nv01 + zv01 * h01; \
      h11 = (1.f - zv11) * nv11 + zv11 * h11; \
      *(short*)(ldsb + oA00) = f2bf(h00); \
      *(short*)(ldsb + oA10) = f2bf(h10); \
      *(short*)(ldsb + oA01) = f2bf(h01); \
      *(short*)(ldsb + oA11) = f2bf(h11); \
      size_t ob = ((size_t)r0 * S_ + (T)) * H_; \
      if (OUT_BF16){ \
        ((short*)outp)[ob + col0]                 = f2bf(h00); \
        ((short*)outp)[ob + col1]                 = f2bf(h10); \
        ((short*)outp)[ob + (size_t)S_*H_ + col0] = f2bf(h01); \
        ((short*)outp)[ob + (size_t)S_*H_ + col1] = f2bf(h11); \
      } else { \
        ((float*)outp)[ob + col0]                 = h00; \
        ((float*)outp)[ob + col1]                 = h10; \
        ((float*)outp)[ob + (size_t)S_*H_ + col0] = h01; \
        ((float*)outp)[ob + (size_t)S_*H_ + col1] = h11; \
      } \
    } \
    bar_lds(); \
  } while (0)

#pragma unroll 1
  for (int t = 0; t < S_; t += 2){
    STEP(t, rgA0, rgB0);
    STEP(t + 1, rgA1, rgB1);
  }
#undef STEP

  if (lk == 0){
    finals[(size_t)r0 * H_ + col0]       = h00;
    finals[(size_t)r0 * H_ + col1]       = h10;
    finals[(size_t)(r0 + 1) * H_ + col0] = h01;
    finals[(size_t)(r0 + 1) * H_ + col1] = h11;
  }
}

// ---------------- launcher ----------------------------------------------------
extern "C" void kernel_launch(void* const* d_in, const int* in_sizes, int n_in,
                              void* d_out, int out_size, void* d_ws, size_t ws_size,
                              hipStream_t stream)
{
  (void)in_sizes; (void)n_in; (void)out_size; (void)ws_size;
  const float* x    = (const float*)d_in[0];
  const float* W_in = (const float*)d_in[1];
  const float* b_in = (const float*)d_in[2];
  const float* Wz   = (const float*)d_in[3];
  const float* bz   = (const float*)d_in[4];
  const float* Wr   = (const float*)d_in[5];
  const float* br   = (const float*)d_in[6];
  const float* Wn   = (const float*)d_in[7];
  const float* bn   = (const float*)d_in[8];
  float* out = (float*)d_out;

  char* ws = (char*)d_ws;
  short* Gbuf  = (short*)(ws + 0);            // [65536][768] bf16 (96MB)
  short* GpA   = (short*)(ws + 100663296);    // chunks*8 bf16 (64MB)
  short* GpB   = (short*)(ws + 167772160);    // chunks*4 bf16 (32MB)
  float* WcT   = (float*)(ws + 201326592);    // [128][768] fp32 tmp
  float* bc    = (float*)(ws + 201719808);    // [768]
  float* bcat1 = (float*)(ws + 201722880);    // [768]
  short* WCF   = (short*)(ws + 201725952);    // Wc frags (NT=48,KT=4)
  short* W1TF  = (short*)(ws + 201922560);    // layer1 top frags (NT=48,KT=8)
  short* WZR0  = (short*)(ws + 202315776);    // layer0 zr bottom frags
  short* WN0   = (short*)(ws + 202577920);    // layer0 n bottom frags
  short* WZR1  = (short*)(ws + 202708992);
  short* WN1   = (short*)(ws + 202971136);
  short* pipe  = (short*)(ws + 203102208);    // h0 sequence bf16 [b][t][256] (32MB)

  prep_compute<<<390, 256, 0, stream>>>(W_in, b_in, Wz, bz, Wr, br, Wn, bn, WcT, bc, bcat1);
  pack_wc <<<384, 256, 0, stream>>>(WCF, WcT);
  pack_top<<<768, 256, 0, stream>>>(W1TF, Wz, Wr, Wn);
  pack_zr <<<512, 256, 0, stream>>>(WZR0, Wz, Wr, 0);
  pack_n  <<<256, 256, 0, stream>>>(WN0, Wn, 0);
  pack_zr <<<512, 256, 0, stream>>>(WZR1, Wz, Wr, 1);
  pack_n  <<<256, 256, 0, stream>>>(WN1, Wn, 1);

  // G0 = x @ Wc + bc -> Gbuf ; repack -> GpA/GpB
  gemm_kernel<false, 4><<<dim3(1024, 6), 256, 0, stream>>>(x, WCF, bc, Gbuf);
  repack<<<16384, 256, 0, stream>>>((const unsigned short*)Gbuf, GpA, GpB);
  // layer 0 recurrence -> h0 pipe (bf16) + h_final[0]
  recur_kernel<true><<<NB_, 512, 0, stream>>>(GpA, GpB, WZR0, WN0, pipe, out + 16777216);
  // P1 = h0 @ W1_top + b1 -> Gbuf ; repack -> GpA/GpB
  gemm_kernel<true, 8><<<dim3(1024, 6), 256, 0, stream>>>(pipe, W1TF, bcat1, Gbuf);
  repack<<<16384, 256, 0, stream>>>((const unsigned short*)Gbuf, GpA, GpB);
  // layer 1 recurrence -> outputs (fp32) + h_final[1]
  recur_kernel<false><<<NB_, 512, 0, stream>>>(GpA, GpB, WZR1, WN1, out, out + 16777216 + 32768);
}

// Round 8
// 2081.639 us; speedup vs baseline: 2.3169x; 1.1153x over previous
//
#include <hip/hip_runtime.h>
#include <stdint.h>

#define B_ 128
#define S_ 512
#define I_ 128
#define H_ 256

#define R_  2          // batch rows per recurrent block
#define NB_ (B_ / R_)  // 64 recurrent blocks

typedef short bf16x8 __attribute__((ext_vector_type(8)));
typedef short bf16x4 __attribute__((ext_vector_type(4)));
typedef float f32x4  __attribute__((ext_vector_type(4)));

__device__ __forceinline__ short f2bf(float f){
  unsigned u = __float_as_uint(f);
  u = (u + 0x7FFFu + ((u >> 16) & 1u)) >> 16;
  return (short)u;
}
__device__ __forceinline__ float bf2f(unsigned short u){
  return __uint_as_float(((unsigned)u) << 16);
}
__device__ __forceinline__ float sigmoidf_(float x){
  float e = __expf(-x);
  return __fdividef(1.f, 1.f + e);
}
__device__ __forceinline__ float tanhf_(float x){
  x = fminf(fmaxf(x, -10.f), 10.f);
  float e = __expf(2.f * x);
  return __fdividef(e - 1.f, e + 1.f);
}
// raw barrier: order LDS ops, do NOT drain vmcnt (keeps global prefetch in flight)
__device__ __forceinline__ void bar_lds(){
  asm volatile("s_waitcnt lgkmcnt(0)" ::: "memory");
  __builtin_amdgcn_s_barrier();
}

#define MF(A, B, C) __builtin_amdgcn_mfma_f32_16x16x32_bf16((A), (B), (C), 0, 0, 0)

// ---------------- prep: combined input weights Wc = W_in @ Wg0_top, biases ----
__global__ __launch_bounds__(256) void prep_compute(
    const float* __restrict__ W_in, const float* __restrict__ b_in,
    const float* __restrict__ Wz, const float* __restrict__ bz,
    const float* __restrict__ Wr, const float* __restrict__ br,
    const float* __restrict__ Wn, const float* __restrict__ bn,
    float* __restrict__ WcT, float* __restrict__ bc, float* __restrict__ bcat1)
{
  int id = blockIdx.x * 256 + threadIdx.x;
  if (id < 98304){                       // Wc[i][gcol] = sum_j W_in[i][j]*Wg[0][j][n]
    int i = id / 768, gcol = id % 768;
    int g = gcol >> 8, n = gcol & 255;
    const float* Wg = (g == 0) ? Wz : (g == 1) ? Wr : Wn;
    float s = 0.f;
    for (int j = 0; j < 256; j++) s += W_in[i * 256 + j] * Wg[j * 256 + n];
    WcT[i * 768 + gcol] = s;
  } else if (id < 99072){                // bc[gcol] = b_in @ Wg0_top + bg0
    int gcol = id - 98304;
    int g = gcol >> 8, n = gcol & 255;
    const float* Wg = (g == 0) ? Wz : (g == 1) ? Wr : Wn;
    const float* bg = (g == 0) ? bz : (g == 1) ? br : bn;
    float s = 0.f;
    for (int j = 0; j < 256; j++) s += b_in[j] * Wg[j * 256 + n];
    bc[gcol] = s + bg[n];
  } else if (id < 99840){                // bcat1[gcol] = bg[1][n]
    int gcol = id - 99072;
    int g = gcol >> 8, n = gcol & 255;
    const float* bg = (g == 0) ? bz : (g == 1) ? br : bn;
    bcat1[gcol] = bg[256 + n];
  }
}

// ---------------- fragment packing -------------------------------------------
// B-frag layout (mfma_f32_16x16x32_bf16): lane l, elem j holds
//   B[kt*32 + (l>>4)*8 + j][nt*16 + (l&15)], stored dst[(((nt*KT+kt)*64+l)*8+j)]

__global__ __launch_bounds__(256) void pack_wc(short* __restrict__ dst, const float* __restrict__ WcT)
{
  int id = blockIdx.x * 256 + threadIdx.x;           // 98304 = 48nt * 4kt * 64 * 8
  int j = id & 7, l = (id >> 3) & 63, kt = (id >> 9) & 3, nt = id >> 11;
  int k = kt * 32 + (l >> 4) * 8 + j;
  int gcol = nt * 16 + (l & 15);
  dst[id] = f2bf(WcT[k * 768 + gcol]);
}

__global__ __launch_bounds__(256) void pack_top(short* __restrict__ dst,
    const float* __restrict__ Wz, const float* __restrict__ Wr, const float* __restrict__ Wn)
{
  int id = blockIdx.x * 256 + threadIdx.x;           // 196608 = 48nt * 8kt * 64 * 8
  int j = id & 7, l = (id >> 3) & 63, kt = (id >> 9) & 7, nt = id >> 12;
  int k = kt * 32 + (l >> 4) * 8 + j;                // 0..255  (layer-1 top half)
  int gcol = nt * 16 + (l & 15);
  int g = gcol >> 8, n = gcol & 255;
  const float* W = (g == 0) ? Wz : (g == 1) ? Wr : Wn;
  dst[id] = f2bf(W[(size_t)(512 + k) * 256 + n]);
}

__global__ __launch_bounds__(256) void pack_zr(short* __restrict__ dst,
    const float* __restrict__ Wz, const float* __restrict__ Wr, int layer)
{
  int id = blockIdx.x * 256 + threadIdx.x;           // 131072 = 32nt * 8kt * 64 * 8
  int j = id & 7, l = (id >> 3) & 63, kt = (id >> 9) & 7, nt = id >> 12;
  int k = kt * 32 + (l >> 4) * 8 + j;                // bottom half (h part)
  int n = (nt & 15) * 16 + (l & 15);
  const float* W = (nt < 16) ? Wz : Wr;
  dst[id] = f2bf(W[((size_t)layer * 512 + 256 + k) * 256 + n]);
}

__global__ __launch_bounds__(256) void pack_n(short* __restrict__ dst,
    const float* __restrict__ Wn, int layer)
{
  int id = blockIdx.x * 256 + threadIdx.x;           // 65536 = 16nt * 8kt * 64 * 8
  int j = id & 7, l = (id >> 3) & 63, kt = (id >> 9) & 7, nt = id >> 12;
  int k = kt * 32 + (l >> 4) * 8 + j;
  int n = nt * 16 + (l & 15);
  dst[id] = f2bf(Wn[((size_t)layer * 512 + 256 + k) * 256 + n]);
}

// ---------------- big parallel GEMM: C[M,768] = A[M,K] @ Bfrags + bias --------
// output bf16 [mrow][768]
template<bool ABF16, int KT>
__global__ __launch_bounds__(256) void gemm_kernel(
    const void* __restrict__ Ap, const short* __restrict__ BF,
    const float* __restrict__ bias, short* __restrict__ C)
{
  const int tid = threadIdx.x, w = tid >> 6, l = tid & 63;
  const int m0 = blockIdx.x * 64 + w * 16;
  const int nb = blockIdx.y;
  const int K = KT * 32;
  f32x4 zero4 = {0.f, 0.f, 0.f, 0.f};
  f32x4 acc[8];
#pragma unroll
  for (int nt = 0; nt < 8; nt++) acc[nt] = zero4;

#pragma unroll
  for (int kt = 0; kt < KT; kt++){
    bf16x8 af;
    if (ABF16){
      af = *(const bf16x8*)((const short*)Ap + (size_t)(m0 + (l & 15)) * K + kt * 32 + (l >> 4) * 8);
    } else {
      const float* A = (const float*)Ap + (size_t)(m0 + (l & 15)) * K + kt * 32 + (l >> 4) * 8;
      f32x4 a0 = *(const f32x4*)A;
      f32x4 a1 = *(const f32x4*)(A + 4);
      af[0] = f2bf(a0[0]); af[1] = f2bf(a0[1]); af[2] = f2bf(a0[2]); af[3] = f2bf(a0[3]);
      af[4] = f2bf(a1[0]); af[5] = f2bf(a1[1]); af[6] = f2bf(a1[2]); af[7] = f2bf(a1[3]);
    }
#pragma unroll
    for (int nt = 0; nt < 8; nt++){
      bf16x8 bf = *(const bf16x8*)(BF + (size_t)(((nb * 8 + nt) * KT + kt) * 64 + l) * 8);
      acc[nt] = __builtin_amdgcn_mfma_f32_16x16x32_bf16(af, bf, acc[nt], 0, 0, 0);
    }
  }
#pragma unroll
  for (int nt = 0; nt < 8; nt++){
    int col = nb * 128 + nt * 16 + (l & 15);
    float bv = bias[col];
#pragma unroll
    for (int rr = 0; rr < 4; rr++){
      int mrow = m0 + (l >> 4) * 4 + rr;
      C[(size_t)mrow * 768 + col] = f2bf(acc[nt][rr] + bv);
    }
  }
}

// ---------------- repack Gbuf -> per-thread chunks ---------------------------
// chunk id = blk*65536 + t*128 + w*16 + cix ; values v[rr*6+i*3+gate]
// GpA[id*8+0..7] = v0..7 ; GpB[id*4+0..3] = v8..11
__global__ __launch_bounds__(256) void repack(const unsigned short* __restrict__ Gbuf,
                                              short* __restrict__ GpA, short* __restrict__ GpB)
{
  int id = blockIdx.x * 256 + threadIdx.x;   // 4,194,304 total
  int cix = id & 15, wv = (id >> 4) & 7, t = (id >> 7) & 511, blk = id >> 16;
  short v[12];
#pragma unroll
  for (int rr = 0; rr < 2; rr++)
#pragma unroll
    for (int i = 0; i < 2; i++)
#pragma unroll
      for (int g = 0; g < 3; g++)
        v[rr * 6 + i * 3 + g] =
          (short)Gbuf[((size_t)(2 * blk + rr) * 512 + t) * 768 + g * 256 + i * 128 + wv * 16 + cix];
  bf16x8 a; bf16x4 b;
#pragma unroll
  for (int j = 0; j < 8; j++) a[j] = v[j];
#pragma unroll
  for (int j = 0; j < 4; j++) b[j] = v[8 + j];
  *(bf16x8*)(GpA + (size_t)id * 8) = a;
  *(bf16x4*)(GpB + (size_t)id * 4) = b;
}

// ---------------- persistent recurrent core ----------------------------------
// 64 blocks x 512 threads (8 waves, 2/SIMD). R7 = scheduling round:
//  - zr loop: 4-deep af-fragment rotation (first 4 ds_read_b128 issued
//    back-to-back after the barrier, next 4 under the first 16 MFMAs)
//  - n loop: 2-deep rotation for af2 + wn weight pairs; first two wn pairs
//    hoisted ABOVE the barrier (static LDS -> legal; hides under gate math)
//  - s_setprio(1) around MFMA bursts
// wzr (128 regs, AGPR-homed), wn in LDS (128KB). VGPR target ~120-126.
// state LDS: hA rows 0,1 @ 0/512 ; zero region @1024..1535 ; rA rows @2048/2560
// swizzle: (row,col) -> row*512 + (((col>>3)^row)<<4) + (col&7)*2
// A-frag read: lane(cix,lk): cix<2 -> cix*512 + ((kt*4+(lk^cix))<<4) ; else 1024 (bcast zero)
template<bool OUT_BF16>
__global__ __launch_bounds__(512, 1) void recur_kernel(
    const short* __restrict__ GpA, const short* __restrict__ GpB,
    const short* __restrict__ WzrF, const short* __restrict__ WnF,
    void* __restrict__ outp, float* __restrict__ finals)
{
  __shared__ __align__(16) char ldsb[4096];
  __shared__ __align__(16) short wnL[65536];   // 128KB: [(w*2+i)*8+kt][lane][8]

  const int tid = threadIdx.x;
  const int w = tid >> 6, l = tid & 63;
  const int cix = l & 15, lk = l >> 4;
  const int r0 = blockIdx.x * R_;
  const int chunkBase = blockIdx.x * 65536 + w * 16 + cix;

  // zero state LDS (h0 = 0, zero-broadcast regions)
  *(uint64_t*)(ldsb + tid * 8) = 0ull;

  // zr weight fragments stay in registers (128 regs/lane, AGPR-homed)
  bf16x8 wzr[4][8];
#pragma unroll
  for (int i = 0; i < 4; i++)
#pragma unroll
    for (int kt = 0; kt < 8; kt++)
      wzr[i][kt] = *(const bf16x8*)(WzrF + (size_t)((((w + 8 * i) * 8 + kt) * 64 + l) * 8));
  // n weight fragments -> LDS (written once; per-lane contiguous 16B)
#pragma unroll
  for (int i = 0; i < 2; i++)
#pragma unroll
    for (int kt = 0; kt < 8; kt++){
      bf16x8 v = *(const bf16x8*)(WnF + (size_t)((((w + 8 * i) * 8 + kt) * 64 + l) * 8));
      *(bf16x8*)(wnL + (size_t)(((w * 2 + i) * 8 + kt) * 64 + l) * 8) = v;
    }
  __syncthreads();

  // A-frag read base (one reg; per-kt offsets are immediates)
  const int A0 = (cix < 2) ? cix * 512 + ((lk ^ cix) << 4) : 1024;
  // wn LDS read bases (shorts): frag block = 64 lanes * 8 shorts = 512
  const short* wn0p = wnL + (size_t)(w * 2 + 0) * 8 * 512 + l * 8;
  const short* wn1p = wnL + (size_t)(w * 2 + 1) * 8 * 512 + l * 8;
  // LDS write offsets (row,col) for lk==0 lanes
  const int col0 = w * 16 + cix, col1 = col0 + 128;
  const int oA00 = col0 * 2;                    // row0, i0
  const int oA10 = col1 * 2;                    // row0, i1
  const int oA01 = 512 + ((col0 * 2) ^ 16);     // row1, i0
  const int oA11 = 512 + ((col1 * 2) ^ 16);     // row1, i1

  float h00 = 0.f, h10 = 0.f, h01 = 0.f, h11 = 0.f;  // h[i][rr]

  // G ring, depth 2
  bf16x8 rgA0{}, rgA1{};
  bf16x4 rgB0{}, rgB1{};
  if (lk == 0){
    rgA0 = *(const bf16x8*)(GpA + (size_t)chunkBase * 8);
    rgB0 = *(const bf16x4*)(GpB + (size_t)chunkBase * 4);
    rgA1 = *(const bf16x8*)(GpA + (size_t)(chunkBase + 128) * 8);
    rgB1 = *(const bf16x4*)(GpB + (size_t)(chunkBase + 128) * 4);
  }

  const f32x4 Z4 = {0.f, 0.f, 0.f, 0.f};

#define AF_ZR(KT) (*(const bf16x8*)(ldsb + A0 + (KT) * 64))
#define AF_N(KT)  (*(const bf16x8*)(ldsb + A0 + (KT) * 64 + 2048))
#define WNL0(KT)  (*(const bf16x8*)(wn0p + (KT) * 512))
#define WNL1(KT)  (*(const bf16x8*)(wn1p + (KT) * 512))

#define STEP(T, RGA, RGB) do { \
    /* ---- zr matmul: 4-deep af rotation ---- */ \
    bf16x8 x0 = AF_ZR(0), x1 = AF_ZR(1), x2 = AF_ZR(2), x3 = AF_ZR(3); \
    f32x4 az0 = Z4, az1 = Z4, ar0 = Z4, ar1 = Z4; \
    __builtin_amdgcn_s_setprio(1); \
    az0 = MF(x0, wzr[0][0], az0); az1 = MF(x0, wzr[1][0], az1); \
    ar0 = MF(x0, wzr[2][0], ar0); ar1 = MF(x0, wzr[3][0], ar1); x0 = AF_ZR(4); \
    az0 = MF(x1, wzr[0][1], az0); az1 = MF(x1, wzr[1][1], az1); \
    ar0 = MF(x1, wzr[2][1], ar0); ar1 = MF(x1, wzr[3][1], ar1); x1 = AF_ZR(5); \
    az0 = MF(x2, wzr[0][2], az0); az1 = MF(x2, wzr[1][2], az1); \
    ar0 = MF(x2, wzr[2][2], ar0); ar1 = MF(x2, wzr[3][2], ar1); x2 = AF_ZR(6); \
    az0 = MF(x3, wzr[0][3], az0); az1 = MF(x3, wzr[1][3], az1); \
    ar0 = MF(x3, wzr[2][3], ar0); ar1 = MF(x3, wzr[3][3], ar1); x3 = AF_ZR(7); \
    az0 = MF(x0, wzr[0][4], az0); az1 = MF(x0, wzr[1][4], az1); \
    ar0 = MF(x0, wzr[2][4], ar0); ar1 = MF(x0, wzr[3][4], ar1); \
    az0 = MF(x1, wzr[0][5], az0); az1 = MF(x1, wzr[1][5], az1); \
    ar0 = MF(x1, wzr[2][5], ar0); ar1 = MF(x1, wzr[3][5], ar1); \
    az0 = MF(x2, wzr[0][6], az0); az1 = MF(x2, wzr[1][6], az1); \
    ar0 = MF(x2, wzr[2][6], ar0); ar1 = MF(x2, wzr[3][6], ar1); \
    az0 = MF(x3, wzr[0][7], az0); az1 = MF(x3, wzr[1][7], az1); \
    ar0 = MF(x3, wzr[2][7], ar0); ar1 = MF(x3, wzr[3][7], ar1); \
    __builtin_amdgcn_s_setprio(0); \
    /* ---- gates z,r ; gn extract ; G prefetch t+2 ; rA write ---- */ \
    float gn00 = 0.f, gn10 = 0.f, gn01 = 0.f, gn11 = 0.f; \
    float zv00 = 0.f, zv10 = 0.f, zv01 = 0.f, zv11 = 0.f; \
    if (lk == 0){ \
      float gz00 = bf2f((unsigned short)RGA[0]), gr00 = bf2f((unsigned short)RGA[1]); \
      gn00 = bf2f((unsigned short)RGA[2]); \
      float gz10 = bf2f((unsigned short)RGA[3]), gr10 = bf2f((unsigned short)RGA[4]); \
      gn10 = bf2f((unsigned short)RGA[5]); \
      float gz01 = bf2f((unsigned short)RGA[6]), gr01 = bf2f((unsigned short)RGA[7]); \
      gn01 = bf2f((unsigned short)RGB[0]); \
      float gz11 = bf2f((unsigned short)RGB[1]), gr11 = bf2f((unsigned short)RGB[2]); \
      gn11 = bf2f((unsigned short)RGB[3]); \
      int tn = (T) + 2; if (tn >= S_) tn = (T); \
      size_t ch = (size_t)chunkBase + (size_t)tn * 128; \
      RGA = *(const bf16x8*)(GpA + ch * 8); \
      RGB = *(const bf16x4*)(GpB + ch * 4); \
      zv00 = sigmoidf_(az0[0] + gz00); zv10 = sigmoidf_(az1[0] + gz10); \
      zv01 = sigmoidf_(az0[1] + gz01); zv11 = sigmoidf_(az1[1] + gz11); \
      float rv00 = sigmoidf_(ar0[0] + gr00), rv10 = sigmoidf_(ar1[0] + gr10); \
      float rv01 = sigmoidf_(ar0[1] + gr01), rv11 = sigmoidf_(ar1[1] + gr11); \
      *(short*)(ldsb + 2048 + oA00) = f2bf(rv00 * h00); \
      *(short*)(ldsb + 2048 + oA10) = f2bf(rv10 * h10); \
      *(short*)(ldsb + 2048 + oA01) = f2bf(rv01 * h01); \
      *(short*)(ldsb + 2048 + oA11) = f2bf(rv11 * h11); \
    } \
    /* hoist first wn pairs above the barrier (static LDS, always legal) */ \
    bf16x8 w00 = WNL0(0), w10 = WNL1(0), w01 = WNL0(1), w11 = WNL1(1); \
    bar_lds(); \
    /* ---- n matmul: 2-deep af2 + wn rotation ---- */ \
    bf16x8 y0 = AF_N(0), y1 = AF_N(1); \
    f32x4 an0 = Z4, an1 = Z4; \
    __builtin_amdgcn_s_setprio(1); \
    an0 = MF(y0, w00, an0); an1 = MF(y0, w10, an1); y0 = AF_N(2); w00 = WNL0(2); w10 = WNL1(2); \
    an0 = MF(y1, w01, an0); an1 = MF(y1, w11, an1); y1 = AF_N(3); w01 = WNL0(3); w11 = WNL1(3); \
    an0 = MF(y0, w00, an0); an1 = MF(y0, w10, an1); y0 = AF_N(4); w00 = WNL0(4); w10 = WNL1(4); \
    an0 = MF(y1, w01, an0); an1 = MF(y1, w11, an1); y1 = AF_N(5); w01 = WNL0(5); w11 = WNL1(5); \
    an0 = MF(y0, w00, an0); an1 = MF(y0, w10, an1); y0 = AF_N(6); w00 = WNL0(6); w10 = WNL1(6); \
    an0 = MF(y1, w01, an0); an1 = MF(y1, w11, an1); y1 = AF_N(7); w01 = WNL0(7); w11 = WNL1(7); \
    an0 = MF(y0, w00, an0); an1 = MF(y0, w10, an1); \
    an0 = MF(y1, w01, an0); an1 = MF(y1, w11, an1); \
    __builtin_amdgcn_s_setprio(0); \
    /* ---- h update + outputs ---- */ \
    if (lk == 0){ \
      float nv00 = tanhf_(an0[0] + gn00), nv10 = tanhf_(an1[0] + gn10); \
      float nv01 = tanhf_(an0[1] + gn01), nv11 = tanhf_(an1[1] + gn11); \
      h00 = (1.f - zv00) * nv00 + zv00 * h00; \
      h10 = (1.f - zv10) * nv10 + zv10 * h10; \
      h01 = (1.f - zv01) * nv01 + zv01 * h01; \
      h11 = (1.f - zv11) * nv11 + zv11 * h11; \
      *(short*)(ldsb + oA00) = f2bf(h00); \
      *(short*)(ldsb + oA10) = f2bf(h10); \
      *(short*)(ldsb + oA01) = f2bf(h01); \
      *(short*)(ldsb + oA11) = f2bf(h11); \
      size_t ob = ((size_t)r0 * S_ + (T)) * H_; \
      if (OUT_BF16){ \
        ((short*)outp)[ob + col0]                 = f2bf(h00); \
        ((short*)outp)[ob + col1]                 = f2bf(h10); \
        ((short*)outp)[ob + (size_t)S_*H_ + col0] = f2bf(h01); \
        ((short*)outp)[ob + (size_t)S_*H_ + col1] = f2bf(h11); \
      } else { \
        ((float*)outp)[ob + col0]                 = h00; \
        ((float*)outp)[ob + col1]                 = h10; \
        ((float*)outp)[ob + (size_t)S_*H_ + col0] = h01; \
        ((float*)outp)[ob + (size_t)S_*H_ + col1] = h11; \
      } \
    } \
    bar_lds(); \
  } while (0)

#pragma unroll 1
  for (int t = 0; t < S_; t += 2){
    STEP(t, rgA0, rgB0);
    STEP(t + 1, rgA1, rgB1);
  }
#undef STEP
#undef AF_ZR
#undef AF_N
#undef WNL0
#undef WNL1

  if (lk == 0){
    finals[(size_t)r0 * H_ + col0]       = h00;
    finals[(size_t)r0 * H_ + col1]       = h10;
    finals[(size_t)(r0 + 1) * H_ + col0] = h01;
    finals[(size_t)(r0 + 1) * H_ + col1] = h11;
  }
}

// ---------------- launcher ----------------------------------------------------
extern "C" void kernel_launch(void* const* d_in, const int* in_sizes, int n_in,
                              void* d_out, int out_size, void* d_ws, size_t ws_size,
                              hipStream_t stream)
{
  (void)in_sizes; (void)n_in; (void)out_size; (void)ws_size;
  const float* x    = (const float*)d_in[0];
  const float* W_in = (const float*)d_in[1];
  const float* b_in = (const float*)d_in[2];
  const float* Wz   = (const float*)d_in[3];
  const float* bz   = (const float*)d_in[4];
  const float* Wr   = (const float*)d_in[5];
  const float* br   = (const float*)d_in[6];
  const float* Wn   = (const float*)d_in[7];
  const float* bn   = (const float*)d_in[8];
  float* out = (float*)d_out;

  char* ws = (char*)d_ws;
  short* Gbuf  = (short*)(ws + 0);            // [65536][768] bf16 (96MB)
  short* GpA   = (short*)(ws + 100663296);    // chunks*8 bf16 (64MB)
  short* GpB   = (short*)(ws + 167772160);    // chunks*4 bf16 (32MB)
  float* WcT   = (float*)(ws + 201326592);    // [128][768] fp32 tmp
  float* bc    = (float*)(ws + 201719808);    // [768]
  float* bcat1 = (float*)(ws + 201722880);    // [768]
  short* WCF   = (short*)(ws + 201725952);    // Wc frags (NT=48,KT=4)
  short* W1TF  = (short*)(ws + 201922560);    // layer1 top frags (NT=48,KT=8)
  short* WZR0  = (short*)(ws + 202315776);    // layer0 zr bottom frags
  short* WN0   = (short*)(ws + 202577920);    // layer0 n bottom frags
  short* WZR1  = (short*)(ws + 202708992);
  short* WN1   = (short*)(ws + 202971136);
  short* pipe  = (short*)(ws + 203102208);    // h0 sequence bf16 [b][t][256] (32MB)

  prep_compute<<<390, 256, 0, stream>>>(W_in, b_in, Wz, bz, Wr, br, Wn, bn, WcT, bc, bcat1);
  pack_wc <<<384, 256, 0, stream>>>(WCF, WcT);
  pack_top<<<768, 256, 0, stream>>>(W1TF, Wz, Wr, Wn);
  pack_zr <<<512, 256, 0, stream>>>(WZR0, Wz, Wr, 0);
  pack_n  <<<256, 256, 0, stream>>>(WN0, Wn, 0);
  pack_zr <<<512, 256, 0, stream>>>(WZR1, Wz, Wr, 1);
  pack_n  <<<256, 256, 0, stream>>>(WN1, Wn, 1);

  // G0 = x @ Wc + bc -> Gbuf ; repack -> GpA/GpB
  gemm_kernel<false, 4><<<dim3(1024, 6), 256, 0, stream>>>(x, WCF, bc, Gbuf);
  repack<<<16384, 256, 0, stream>>>((const unsigned short*)Gbuf, GpA, GpB);
  // layer 0 recurrence -> h0 pipe (bf16) + h_final[0]
  recur_kernel<true><<<NB_, 512, 0, stream>>>(GpA, GpB, WZR0, WN0, pipe, out + 16777216);
  // P1 = h0 @ W1_top + b1 -> Gbuf ; repack -> GpA/GpB
  gemm_kernel<true, 8><<<dim3(1024, 6), 256, 0, stream>>>(pipe, W1TF, bcat1, Gbuf);
  repack<<<16384, 256, 0, stream>>>((const unsigned short*)Gbuf, GpA, GpB);
  // layer 1 recurrence -> outputs (fp32) + h_final[1]
  recur_kernel<false><<<NB_, 512, 0, stream>>>(GpA, GpB, WZR1, WN1, out, out + 16777216 + 32768);
}

// Round 9
// 1490.954 us; speedup vs baseline: 3.2348x; 1.3962x over previous
//
#include <hip/hip_runtime.h>
#include <stdint.h>

#define B_ 128
#define S_ 512
#define I_ 128
#define H_ 256

typedef short bf16x8 __attribute__((ext_vector_type(8)));
typedef short bf16x4 __attribute__((ext_vector_type(4)));
typedef float f32x4  __attribute__((ext_vector_type(4)));

__device__ __forceinline__ short f2bf(float f){
  unsigned u = __float_as_uint(f);
  u = (u + 0x7FFFu + ((u >> 16) & 1u)) >> 16;
  return (short)u;
}
__device__ __forceinline__ float bf2f(unsigned short u){
  return __uint_as_float(((unsigned)u) << 16);
}
__device__ __forceinline__ float sigmoidf_(float x){
  float e = __expf(-x);
  return __fdividef(1.f, 1.f + e);
}
__device__ __forceinline__ float tanhf_(float x){
  x = fminf(fmaxf(x, -10.f), 10.f);
  float e = __expf(2.f * x);
  return __fdividef(e - 1.f, e + 1.f);
}
// raw barrier: order LDS ops, do NOT drain vmcnt (keeps global prefetch in flight)
__device__ __forceinline__ void bar_lds(){
  asm volatile("s_waitcnt lgkmcnt(0)" ::: "memory");
  __builtin_amdgcn_s_barrier();
}

#define MF(A, B, C) __builtin_amdgcn_mfma_f32_16x16x32_bf16((A), (B), (C), 0, 0, 0)

// ---------------- prep: combined input weights Wc = W_in @ Wg0_top, biases ----
__global__ __launch_bounds__(256) void prep_compute(
    const float* __restrict__ W_in, const float* __restrict__ b_in,
    const float* __restrict__ Wz, const float* __restrict__ bz,
    const float* __restrict__ Wr, const float* __restrict__ br,
    const float* __restrict__ Wn, const float* __restrict__ bn,
    float* __restrict__ WcT, float* __restrict__ bc, float* __restrict__ bcat1)
{
  int id = blockIdx.x * 256 + threadIdx.x;
  if (id < 98304){                       // Wc[i][gcol] = sum_j W_in[i][j]*Wg[0][j][n]
    int i = id / 768, gcol = id % 768;
    int g = gcol >> 8, n = gcol & 255;
    const float* Wg = (g == 0) ? Wz : (g == 1) ? Wr : Wn;
    float s = 0.f;
    for (int j = 0; j < 256; j++) s += W_in[i * 256 + j] * Wg[j * 256 + n];
    WcT[i * 768 + gcol] = s;
  } else if (id < 99072){                // bc[gcol] = b_in @ Wg0_top + bg0
    int gcol = id - 98304;
    int g = gcol >> 8, n = gcol & 255;
    const float* Wg = (g == 0) ? Wz : (g == 1) ? Wr : Wn;
    const float* bg = (g == 0) ? bz : (g == 1) ? br : bn;
    float s = 0.f;
    for (int j = 0; j < 256; j++) s += b_in[j] * Wg[j * 256 + n];
    bc[gcol] = s + bg[n];
  } else if (id < 99840){                // bcat1[gcol] = bg[1][n]
    int gcol = id - 99072;
    int g = gcol >> 8, n = gcol & 255;
    const float* bg = (g == 0) ? bz : (g == 1) ? br : bn;
    bcat1[gcol] = bg[256 + n];
  }
}

// ---------------- fragment packing -------------------------------------------
// B-frag layout (mfma_f32_16x16x32_bf16): lane l, elem j holds
//   B[kt*32 + (l>>4)*8 + j][nt*16 + (l&15)], stored dst[(((nt*KT+kt)*64+l)*8+j)]

__global__ __launch_bounds__(256) void pack_wc(short* __restrict__ dst, const float* __restrict__ WcT)
{
  int id = blockIdx.x * 256 + threadIdx.x;           // 98304 = 48nt * 4kt * 64 * 8
  int j = id & 7, l = (id >> 3) & 63, kt = (id >> 9) & 3, nt = id >> 11;
  int k = kt * 32 + (l >> 4) * 8 + j;
  int gcol = nt * 16 + (l & 15);
  dst[id] = f2bf(WcT[k * 768 + gcol]);
}

__global__ __launch_bounds__(256) void pack_top(short* __restrict__ dst,
    const float* __restrict__ Wz, const float* __restrict__ Wr, const float* __restrict__ Wn)
{
  int id = blockIdx.x * 256 + threadIdx.x;           // 196608 = 48nt * 8kt * 64 * 8
  int j = id & 7, l = (id >> 3) & 63, kt = (id >> 9) & 7, nt = id >> 12;
  int k = kt * 32 + (l >> 4) * 8 + j;                // 0..255  (layer-1 top half)
  int gcol = nt * 16 + (l & 15);
  int g = gcol >> 8, n = gcol & 255;
  const float* W = (g == 0) ? Wz : (g == 1) ? Wr : Wn;
  dst[id] = f2bf(W[(size_t)(512 + k) * 256 + n]);
}

__global__ __launch_bounds__(256) void pack_zr(short* __restrict__ dst,
    const float* __restrict__ Wz, const float* __restrict__ Wr, int layer)
{
  int id = blockIdx.x * 256 + threadIdx.x;           // 131072 = 32nt * 8kt * 64 * 8
  int j = id & 7, l = (id >> 3) & 63, kt = (id >> 9) & 7, nt = id >> 12;
  int k = kt * 32 + (l >> 4) * 8 + j;                // bottom half (h part)
  int n = (nt & 15) * 16 + (l & 15);
  const float* W = (nt < 16) ? Wz : Wr;
  dst[id] = f2bf(W[((size_t)layer * 512 + 256 + k) * 256 + n]);
}

__global__ __launch_bounds__(256) void pack_n(short* __restrict__ dst,
    const float* __restrict__ Wn, int layer)
{
  int id = blockIdx.x * 256 + threadIdx.x;           // 65536 = 16nt * 8kt * 64 * 8
  int j = id & 7, l = (id >> 3) & 63, kt = (id >> 9) & 7, nt = id >> 12;
  int k = kt * 32 + (l >> 4) * 8 + j;
  int n = nt * 16 + (l & 15);
  dst[id] = f2bf(Wn[((size_t)layer * 512 + 256 + k) * 256 + n]);
}

// ---------------- big parallel GEMM: C[M,768] = A[M,K] @ Bfrags + bias --------
// output bf16 [mrow][768]
template<bool ABF16, int KT>
__global__ __launch_bounds__(256) void gemm_kernel(
    const void* __restrict__ Ap, const short* __restrict__ BF,
    const float* __restrict__ bias, short* __restrict__ C)
{
  const int tid = threadIdx.x, w = tid >> 6, l = tid & 63;
  const int m0 = blockIdx.x * 64 + w * 16;
  const int nb = blockIdx.y;
  const int K = KT * 32;
  f32x4 zero4 = {0.f, 0.f, 0.f, 0.f};
  f32x4 acc[8];
#pragma unroll
  for (int nt = 0; nt < 8; nt++) acc[nt] = zero4;

#pragma unroll
  for (int kt = 0; kt < KT; kt++){
    bf16x8 af;
    if (ABF16){
      af = *(const bf16x8*)((const short*)Ap + (size_t)(m0 + (l & 15)) * K + kt * 32 + (l >> 4) * 8);
    } else {
      const float* A = (const float*)Ap + (size_t)(m0 + (l & 15)) * K + kt * 32 + (l >> 4) * 8;
      f32x4 a0 = *(const f32x4*)A;
      f32x4 a1 = *(const f32x4*)(A + 4);
      af[0] = f2bf(a0[0]); af[1] = f2bf(a0[1]); af[2] = f2bf(a0[2]); af[3] = f2bf(a0[3]);
      af[4] = f2bf(a1[0]); af[5] = f2bf(a1[1]); af[6] = f2bf(a1[2]); af[7] = f2bf(a1[3]);
    }
#pragma unroll
    for (int nt = 0; nt < 8; nt++){
      bf16x8 bf = *(const bf16x8*)(BF + (size_t)(((nb * 8 + nt) * KT + kt) * 64 + l) * 8);
      acc[nt] = __builtin_amdgcn_mfma_f32_16x16x32_bf16(af, bf, acc[nt], 0, 0, 0);
    }
  }
#pragma unroll
  for (int nt = 0; nt < 8; nt++){
    int col = nb * 128 + nt * 16 + (l & 15);
    float bv = bias[col];
#pragma unroll
    for (int rr = 0; rr < 4; rr++){
      int mrow = m0 + (l >> 4) * 4 + rr;
      C[(size_t)mrow * 768 + col] = f2bf(acc[nt][rr] + bv);
    }
  }
}

// ---------------- repack Gbuf -> per-thread 6-value chunks (R=1) -------------
// chunk id = ((row*S + t)*128 + w*16 + cix); values v[i*3+g], i=col-block, g=z/r/n
// GpA4[id] = {v0,v1,v2,v3} ; GpB2[id] = v4 | v5<<16
__global__ __launch_bounds__(256) void repack6(const unsigned short* __restrict__ Gbuf,
                                               short* __restrict__ GpA4, unsigned* __restrict__ GpB2)
{
  int id = blockIdx.x * 256 + threadIdx.x;   // 8,388,608 total
  int cix = id & 15, wv = (id >> 4) & 7, t = (id >> 7) & 511, row = id >> 16;
  short v[6];
#pragma unroll
  for (int i = 0; i < 2; i++)
#pragma unroll
    for (int g = 0; g < 3; g++)
      v[i * 3 + g] =
        (short)Gbuf[((size_t)row * 512 + t) * 768 + g * 256 + i * 128 + wv * 16 + cix];
  bf16x4 a = {v[0], v[1], v[2], v[3]};
  *(bf16x4*)(GpA4 + (size_t)id * 4) = a;
  GpB2[id] = (unsigned)(unsigned short)v[4] | ((unsigned)(unsigned short)v[5] << 16);
}

// ---------------- persistent recurrent core (R=1) -----------------------------
// 128 blocks x 512 threads (8 waves, 2/SIMD). Block = 1 batch row.
// ALL weights register-resident (wzr 128 + wn 64, AGPR-homed by regalloc,
// consumed directly by builtin MFMA — no LDS weight traffic, no spills).
// LDS 4KB state only:
//   hA row0 @0..511 ; zero region @1024..1535 ; rA row0 @2048..2559 ;
//   (rA zero = 3072..3583). Swizzle trivial for row0 (identity).
// A-frag read: lane(cix,lk): cix==0 -> (kt*4+lk)<<4 ; else 1024 (bcast zero)
// R7 scheduling kept: 4-deep af rotation (zr), 2-deep (n), setprio around MFMA.
template<bool OUT_BF16>
__global__ __launch_bounds__(512, 1) void recur_kernel(
    const short* __restrict__ GpA4, const unsigned* __restrict__ GpB2,
    const short* __restrict__ WzrF, const short* __restrict__ WnF,
    void* __restrict__ outp, float* __restrict__ finals)
{
  __shared__ __align__(16) char ldsb[4096];

  const int tid = threadIdx.x;
  const int w = tid >> 6, l = tid & 63;
  const int cix = l & 15, lk = l >> 4;
  const int r0 = blockIdx.x;                 // batch row
  const int chunkBase = blockIdx.x * 65536 + w * 16 + cix;

  // zero state LDS (h0 = 0, zero-broadcast regions)
  *(uint64_t*)(ldsb + tid * 8) = 0ull;

  // weight fragments, all register-resident (AGPR-homed)
  bf16x8 wzr[4][8];
  bf16x8 wn[2][8];
#pragma unroll
  for (int i = 0; i < 4; i++)
#pragma unroll
    for (int kt = 0; kt < 8; kt++)
      wzr[i][kt] = *(const bf16x8*)(WzrF + (size_t)((((w + 8 * i) * 8 + kt) * 64 + l) * 8));
#pragma unroll
  for (int i = 0; i < 2; i++)
#pragma unroll
    for (int kt = 0; kt < 8; kt++)
      wn[i][kt] = *(const bf16x8*)(WnF + (size_t)((((w + 8 * i) * 8 + kt) * 64 + l) * 8));
  __syncthreads();

  // A-frag read base (row0 only real; others broadcast zero @1024)
  const int A0 = (cix == 0) ? (lk << 4) : 1024;
  // LDS write offsets (row0, identity swizzle) for lk==0 lanes
  const int col0 = w * 16 + cix, col1 = col0 + 128;
  const int oA00 = col0 * 2;
  const int oA10 = col1 * 2;

  float h00 = 0.f, h10 = 0.f;   // h[i] for col0/col1 blocks

  // G ring, depth 2
  bf16x4 rgA0{}, rgA1{};
  unsigned rgB0 = 0, rgB1 = 0;
  if (lk == 0){
    rgA0 = *(const bf16x4*)(GpA4 + (size_t)chunkBase * 4);
    rgB0 = GpB2[chunkBase];
    rgA1 = *(const bf16x4*)(GpA4 + (size_t)(chunkBase + 128) * 4);
    rgB1 = GpB2[chunkBase + 128];
  }

  const f32x4 Z4 = {0.f, 0.f, 0.f, 0.f};

#define AF_ZR(KT) (*(const bf16x8*)(ldsb + A0 + (KT) * 64))
#define AF_N(KT)  (*(const bf16x8*)(ldsb + A0 + (KT) * 64 + 2048))

#define STEP(T, RGA, RGB) do { \
    /* ---- zr matmul: 4-deep af rotation ---- */ \
    bf16x8 x0 = AF_ZR(0), x1 = AF_ZR(1), x2 = AF_ZR(2), x3 = AF_ZR(3); \
    f32x4 az0 = Z4, az1 = Z4, ar0 = Z4, ar1 = Z4; \
    __builtin_amdgcn_s_setprio(1); \
    az0 = MF(x0, wzr[0][0], az0); az1 = MF(x0, wzr[1][0], az1); \
    ar0 = MF(x0, wzr[2][0], ar0); ar1 = MF(x0, wzr[3][0], ar1); x0 = AF_ZR(4); \
    az0 = MF(x1, wzr[0][1], az0); az1 = MF(x1, wzr[1][1], az1); \
    ar0 = MF(x1, wzr[2][1], ar0); ar1 = MF(x1, wzr[3][1], ar1); x1 = AF_ZR(5); \
    az0 = MF(x2, wzr[0][2], az0); az1 = MF(x2, wzr[1][2], az1); \
    ar0 = MF(x2, wzr[2][2], ar0); ar1 = MF(x2, wzr[3][2], ar1); x2 = AF_ZR(6); \
    az0 = MF(x3, wzr[0][3], az0); az1 = MF(x3, wzr[1][3], az1); \
    ar0 = MF(x3, wzr[2][3], ar0); ar1 = MF(x3, wzr[3][3], ar1); x3 = AF_ZR(7); \
    az0 = MF(x0, wzr[0][4], az0); az1 = MF(x0, wzr[1][4], az1); \
    ar0 = MF(x0, wzr[2][4], ar0); ar1 = MF(x0, wzr[3][4], ar1); \
    az0 = MF(x1, wzr[0][5], az0); az1 = MF(x1, wzr[1][5], az1); \
    ar0 = MF(x1, wzr[2][5], ar0); ar1 = MF(x1, wzr[3][5], ar1); \
    az0 = MF(x2, wzr[0][6], az0); az1 = MF(x2, wzr[1][6], az1); \
    ar0 = MF(x2, wzr[2][6], ar0); ar1 = MF(x2, wzr[3][6], ar1); \
    az0 = MF(x3, wzr[0][7], az0); az1 = MF(x3, wzr[1][7], az1); \
    ar0 = MF(x3, wzr[2][7], ar0); ar1 = MF(x3, wzr[3][7], ar1); \
    __builtin_amdgcn_s_setprio(0); \
    /* ---- gates z,r ; G prefetch t+2 ; rA write ---- */ \
    float gn00 = 0.f, gn10 = 0.f; \
    float zv00 = 0.f, zv10 = 0.f; \
    if (lk == 0){ \
      float gz00 = bf2f((unsigned short)RGA[0]), gr00 = bf2f((unsigned short)RGA[1]); \
      gn00 = bf2f((unsigned short)RGA[2]); \
      float gz10 = bf2f((unsigned short)RGA[3]); \
      float gr10 = bf2f((unsigned short)(RGB & 0xffffu)); \
      gn10 = bf2f((unsigned short)(RGB >> 16)); \
      int tn = (T) + 2; if (tn >= S_) tn = (T); \
      size_t ch = (size_t)chunkBase + (size_t)tn * 128; \
      RGA = *(const bf16x4*)(GpA4 + ch * 4); \
      RGB = GpB2[ch]; \
      zv00 = sigmoidf_(az0[0] + gz00); zv10 = sigmoidf_(az1[0] + gz10); \
      float rv00 = sigmoidf_(ar0[0] + gr00), rv10 = sigmoidf_(ar1[0] + gr10); \
      *(short*)(ldsb + 2048 + oA00) = f2bf(rv00 * h00); \
      *(short*)(ldsb + 2048 + oA10) = f2bf(rv10 * h10); \
    } \
    bar_lds(); \
    /* ---- n matmul: 2-deep af rotation, weights in regs ---- */ \
    bf16x8 y0 = AF_N(0), y1 = AF_N(1); \
    f32x4 an0 = Z4, an1 = Z4; \
    __builtin_amdgcn_s_setprio(1); \
    an0 = MF(y0, wn[0][0], an0); an1 = MF(y0, wn[1][0], an1); y0 = AF_N(2); \
    an0 = MF(y1, wn[0][1], an0); an1 = MF(y1, wn[1][1], an1); y1 = AF_N(3); \
    an0 = MF(y0, wn[0][2], an0); an1 = MF(y0, wn[1][2], an1); y0 = AF_N(4); \
    an0 = MF(y1, wn[0][3], an0); an1 = MF(y1, wn[1][3], an1); y1 = AF_N(5); \
    an0 = MF(y0, wn[0][4], an0); an1 = MF(y0, wn[1][4], an1); y0 = AF_N(6); \
    an0 = MF(y1, wn[0][5], an0); an1 = MF(y1, wn[1][5], an1); y1 = AF_N(7); \
    an0 = MF(y0, wn[0][6], an0); an1 = MF(y0, wn[1][6], an1); \
    an0 = MF(y1, wn[0][7], an0); an1 = MF(y1, wn[1][7], an1); \
    __builtin_amdgcn_s_setprio(0); \
    /* ---- h update + outputs ---- */ \
    if (lk == 0){ \
      float nv00 = tanhf_(an0[0] + gn00), nv10 = tanhf_(an1[0] + gn10); \
      h00 = (1.f - zv00) * nv00 + zv00 * h00; \
      h10 = (1.f - zv10) * nv10 + zv10 * h10; \
      *(short*)(ldsb + oA00) = f2bf(h00); \
      *(short*)(ldsb + oA10) = f2bf(h10); \
      size_t ob = ((size_t)r0 * S_ + (T)) * H_; \
      if (OUT_BF16){ \
        ((short*)outp)[ob + col0] = f2bf(h00); \
        ((short*)outp)[ob + col1] = f2bf(h10); \
      } else { \
        ((float*)outp)[ob + col0] = h00; \
        ((float*)outp)[ob + col1] = h10; \
      } \
    } \
    bar_lds(); \
  } while (0)

#pragma unroll 1
  for (int t = 0; t < S_; t += 2){
    STEP(t, rgA0, rgB0);
    STEP(t + 1, rgA1, rgB1);
  }
#undef STEP
#undef AF_ZR
#undef AF_N

  if (lk == 0){
    finals[(size_t)r0 * H_ + col0] = h00;
    finals[(size_t)r0 * H_ + col1] = h10;
  }
}

// ---------------- launcher ----------------------------------------------------
extern "C" void kernel_launch(void* const* d_in, const int* in_sizes, int n_in,
                              void* d_out, int out_size, void* d_ws, size_t ws_size,
                              hipStream_t stream)
{
  (void)in_sizes; (void)n_in; (void)out_size; (void)ws_size;
  const float* x    = (const float*)d_in[0];
  const float* W_in = (const float*)d_in[1];
  const float* b_in = (const float*)d_in[2];
  const float* Wz   = (const float*)d_in[3];
  const float* bz   = (const float*)d_in[4];
  const float* Wr   = (const float*)d_in[5];
  const float* br   = (const float*)d_in[6];
  const float* Wn   = (const float*)d_in[7];
  const float* bn   = (const float*)d_in[8];
  float* out = (float*)d_out;

  char* ws = (char*)d_ws;
  short*    Gbuf  = (short*)(ws + 0);            // [65536][768] bf16 (96MB)
  short*    GpA4  = (short*)(ws + 100663296);    // 8.4M chunks * 8B (64MB)
  unsigned* GpB2  = (unsigned*)(ws + 167772160); // 8.4M chunks * 4B (32MB)
  float* WcT   = (float*)(ws + 201326592);    // [128][768] fp32 tmp
  float* bc    = (float*)(ws + 201719808);    // [768]
  float* bcat1 = (float*)(ws + 201722880);    // [768]
  short* WCF   = (short*)(ws + 201725952);    // Wc frags (NT=48,KT=4)
  short* W1TF  = (short*)(ws + 201922560);    // layer1 top frags (NT=48,KT=8)
  short* WZR0  = (short*)(ws + 202315776);    // layer0 zr bottom frags
  short* WN0   = (short*)(ws + 202577920);    // layer0 n bottom frags
  short* WZR1  = (short*)(ws + 202708992);
  short* WN1   = (short*)(ws + 202971136);
  short* pipe  = (short*)(ws + 203102208);    // h0 sequence bf16 [b][t][256] (32MB)

  prep_compute<<<390, 256, 0, stream>>>(W_in, b_in, Wz, bz, Wr, br, Wn, bn, WcT, bc, bcat1);
  pack_wc <<<384, 256, 0, stream>>>(WCF, WcT);
  pack_top<<<768, 256, 0, stream>>>(W1TF, Wz, Wr, Wn);
  pack_zr <<<512, 256, 0, stream>>>(WZR0, Wz, Wr, 0);
  pack_n  <<<256, 256, 0, stream>>>(WN0, Wn, 0);
  pack_zr <<<512, 256, 0, stream>>>(WZR1, Wz, Wr, 1);
  pack_n  <<<256, 256, 0, stream>>>(WN1, Wn, 1);

  // G0 = x @ Wc + bc -> Gbuf ; repack6 -> GpA4/GpB2
  gemm_kernel<false, 4><<<dim3(1024, 6), 256, 0, stream>>>(x, WCF, bc, Gbuf);
  repack6<<<32768, 256, 0, stream>>>((const unsigned short*)Gbuf, GpA4, GpB2);
  // layer 0 recurrence (128 blocks, 1 row each) -> h0 pipe (bf16) + h_final[0]
  recur_kernel<true><<<B_, 512, 0, stream>>>(GpA4, GpB2, WZR0, WN0, pipe, out + 16777216);
  // P1 = h0 @ W1_top + b1 -> Gbuf ; repack6
  gemm_kernel<true, 8><<<dim3(1024, 6), 256, 0, stream>>>(pipe, W1TF, bcat1, Gbuf);
  repack6<<<32768, 256, 0, stream>>>((const unsigned short*)Gbuf, GpA4, GpB2);
  // layer 1 recurrence -> outputs (fp32) + h_final[1]
  recur_kernel<false><<<B_, 512, 0, stream>>>(GpA4, GpB2, WZR1, WN1, out, out + 16777216 + 32768);
}

// Round 10
// 1298.679 us; speedup vs baseline: 3.7137x; 1.1481x over previous
//
#include <hip/hip_runtime.h>
#include <stdint.h>

#define B_ 128
#define S_ 512
#define I_ 128
#define H_ 256

typedef short bf16x8 __attribute__((ext_vector_type(8)));
typedef short bf16x4 __attribute__((ext_vector_type(4)));
typedef float f32x4  __attribute__((ext_vector_type(4)));

__device__ __forceinline__ short f2bf(float f){
  unsigned u = __float_as_uint(f);
  u = (u + 0x7FFFu + ((u >> 16) & 1u)) >> 16;
  return (short)u;
}
__device__ __forceinline__ float bf2f(unsigned short u){
  return __uint_as_float(((unsigned)u) << 16);
}
__device__ __forceinline__ float sigmoidf_(float x){
  float e = __expf(-x);
  return __fdividef(1.f, 1.f + e);
}
__device__ __forceinline__ float tanhf_(float x){
  x = fminf(fmaxf(x, -10.f), 10.f);
  float e = __expf(2.f * x);
  return __fdividef(e - 1.f, e + 1.f);
}
__device__ __forceinline__ void bar_lds(){
  asm volatile("s_waitcnt lgkmcnt(0)" ::: "memory");
  __builtin_amdgcn_s_barrier();
}
#define MF(A, B, C) __builtin_amdgcn_mfma_f32_16x16x32_bf16((A), (B), (C), 0, 0, 0)

// ---------------- prep ---------------------------------------------------------
__global__ __launch_bounds__(256) void prep_compute(
    const float* __restrict__ W_in, const float* __restrict__ b_in,
    const float* __restrict__ Wz, const float* __restrict__ bz,
    const float* __restrict__ Wr, const float* __restrict__ br,
    const float* __restrict__ Wn, const float* __restrict__ bn,
    float* __restrict__ WcT, float* __restrict__ bc, float* __restrict__ bcat1)
{
  int id = blockIdx.x * 256 + threadIdx.x;
  if (id < 98304){
    int i = id / 768, gcol = id % 768;
    int g = gcol >> 8, n = gcol & 255;
    const float* Wg = (g == 0) ? Wz : (g == 1) ? Wr : Wn;
    float s = 0.f;
    for (int j = 0; j < 256; j++) s += W_in[i * 256 + j] * Wg[j * 256 + n];
    WcT[i * 768 + gcol] = s;
  } else if (id < 99072){
    int gcol = id - 98304;
    int g = gcol >> 8, n = gcol & 255;
    const float* Wg = (g == 0) ? Wz : (g == 1) ? Wr : Wn;
    const float* bg = (g == 0) ? bz : (g == 1) ? br : bn;
    float s = 0.f;
    for (int j = 0; j < 256; j++) s += b_in[j] * Wg[j * 256 + n];
    bc[gcol] = s + bg[n];
  } else if (id < 99840){
    int gcol = id - 99072;
    int g = gcol >> 8, n = gcol & 255;
    const float* bg = (g == 0) ? bz : (g == 1) ? br : bn;
    bcat1[gcol] = bg[256 + n];
  }
}

// ---------------- fragment packing --------------------------------------------
__global__ __launch_bounds__(256) void pack_wc(short* __restrict__ dst, const float* __restrict__ WcT)
{
  int id = blockIdx.x * 256 + threadIdx.x;
  int j = id & 7, l = (id >> 3) & 63, kt = (id >> 9) & 3, nt = id >> 11;
  int k = kt * 32 + (l >> 4) * 8 + j;
  int gcol = nt * 16 + (l & 15);
  dst[id] = f2bf(WcT[k * 768 + gcol]);
}

__global__ __launch_bounds__(256) void pack_top(short* __restrict__ dst,
    const float* __restrict__ Wz, const float* __restrict__ Wr, const float* __restrict__ Wn)
{
  int id = blockIdx.x * 256 + threadIdx.x;
  int j = id & 7, l = (id >> 3) & 63, kt = (id >> 9) & 7, nt = id >> 12;
  int k = kt * 32 + (l >> 4) * 8 + j;
  int gcol = nt * 16 + (l & 15);
  int g = gcol >> 8, n = gcol & 255;
  const float* W = (g == 0) ? Wz : (g == 1) ? Wr : Wn;
  dst[id] = f2bf(W[(size_t)(512 + k) * 256 + n]);
}

__global__ __launch_bounds__(256) void pack_zr(short* __restrict__ dst,
    const float* __restrict__ Wz, const float* __restrict__ Wr, int layer)
{
  int id = blockIdx.x * 256 + threadIdx.x;
  int j = id & 7, l = (id >> 3) & 63, kt = (id >> 9) & 7, nt = id >> 12;
  int k = kt * 32 + (l >> 4) * 8 + j;
  int n = (nt & 15) * 16 + (l & 15);
  const float* W = (nt < 16) ? Wz : Wr;
  dst[id] = f2bf(W[((size_t)layer * 512 + 256 + k) * 256 + n]);
}

__global__ __launch_bounds__(256) void pack_n(short* __restrict__ dst,
    const float* __restrict__ Wn, int layer)
{
  int id = blockIdx.x * 256 + threadIdx.x;
  int j = id & 7, l = (id >> 3) & 63, kt = (id >> 9) & 7, nt = id >> 12;
  int k = kt * 32 + (l >> 4) * 8 + j;
  int n = nt * 16 + (l & 15);
  dst[id] = f2bf(Wn[((size_t)layer * 512 + 256 + k) * 256 + n]);
}

// ---------------- G0 GEMM: C[M,768] = x[M,128] @ WcF + bc ----------------------
__global__ __launch_bounds__(256) void gemm_g0(
    const float* __restrict__ Ap, const short* __restrict__ BF,
    const float* __restrict__ bias, short* __restrict__ C)
{
  const int tid = threadIdx.x, w = tid >> 6, l = tid & 63;
  const int m0 = blockIdx.x * 64 + w * 16;
  const int nb = blockIdx.y;
  const int K = 128;
  f32x4 zero4 = {0.f, 0.f, 0.f, 0.f};
  f32x4 acc[8];
#pragma unroll
  for (int nt = 0; nt < 8; nt++) acc[nt] = zero4;
#pragma unroll
  for (int kt = 0; kt < 4; kt++){
    const float* A = Ap + (size_t)(m0 + (l & 15)) * K + kt * 32 + (l >> 4) * 8;
    f32x4 a0 = *(const f32x4*)A;
    f32x4 a1 = *(const f32x4*)(A + 4);
    bf16x8 af;
    af[0] = f2bf(a0[0]); af[1] = f2bf(a0[1]); af[2] = f2bf(a0[2]); af[3] = f2bf(a0[3]);
    af[4] = f2bf(a1[0]); af[5] = f2bf(a1[1]); af[6] = f2bf(a1[2]); af[7] = f2bf(a1[3]);
#pragma unroll
    for (int nt = 0; nt < 8; nt++){
      bf16x8 bf = *(const bf16x8*)(BF + (size_t)(((nb * 8 + nt) * 4 + kt) * 64 + l) * 8);
      acc[nt] = MF(af, bf, acc[nt]);
    }
  }
#pragma unroll
  for (int nt = 0; nt < 8; nt++){
    int col = nb * 128 + nt * 16 + (l & 15);
    float bv = bias[col];
#pragma unroll
    for (int rr = 0; rr < 4; rr++){
      int mrow = m0 + (l >> 4) * 4 + rr;
      C[(size_t)mrow * 768 + col] = f2bf(acc[nt][rr] + bv);
    }
  }
}

// ---------------- repack Gbuf -> per-thread 6-value chunks (layer0) ------------
__global__ __launch_bounds__(256) void repack6(const unsigned short* __restrict__ Gbuf,
                                               short* __restrict__ GpA4, unsigned* __restrict__ GpB2)
{
  int id = blockIdx.x * 256 + threadIdx.x;
  int cix = id & 15, wv = (id >> 4) & 7, t = (id >> 7) & 511, row = id >> 16;
  short v[6];
#pragma unroll
  for (int i = 0; i < 2; i++)
#pragma unroll
    for (int g = 0; g < 3; g++)
      v[i * 3 + g] =
        (short)Gbuf[((size_t)row * 512 + t) * 768 + g * 256 + i * 128 + wv * 16 + cix];
  bf16x4 a = {v[0], v[1], v[2], v[3]};
  *(bf16x4*)(GpA4 + (size_t)id * 4) = a;
  GpB2[id] = (unsigned)(unsigned short)v[4] | ((unsigned)(unsigned short)v[5] << 16);
}

// ---------------- fused dual-layer persistent kernel ---------------------------
// 256 blocks x 512 threads, all co-resident (1 block/CU; dependency is strictly
// L0 -> L1 so any placement is deadlock-free).
//  blocks 0..127   : layer-0 recurrence (R8 structure) -> pipe (bf16) + finals0;
//                    every 16 steps: __syncthreads (drains vmcnt for all waves,
//                    all stores reach L2) then tid0 AGENT-release flag store
//                    (emits L2 writeback -> visible cross-XCD).
//  blocks 128..255 : layer-1 for row b-128. Per 16-step chunk: acquire-spin on
//                    flag, load h0 chunk, P1 chunk-GEMM with TIMESTEPS IN M
//                    ([16,256]@[256,768], full-M, W1top streamed from L2) ->
//                    p1L LDS; then 16 recurrence steps (wzr1 in regs, wn1 in
//                    LDS per R6) -> fp32 out + finals1.
__global__ __launch_bounds__(512, 1) void fused_recur(
    const short* __restrict__ GpA4, const unsigned* __restrict__ GpB2,
    const short* __restrict__ WZR0F, const short* __restrict__ WN0F,
    const short* __restrict__ WZR1F, const short* __restrict__ WN1F,
    const short* __restrict__ W1TF, const float* __restrict__ bcat1,
    short* __restrict__ pipe, float* __restrict__ out,
    float* __restrict__ finals, unsigned* __restrict__ flags)
{
  __shared__ __align__(16) char  ldsb[4096];    // h/rA state + zero regions
  __shared__ __align__(16) short wnL[65536];    // layer1 wn frags (128KB)
  __shared__ __align__(16) short p1L[12288];    // layer1 P1 chunk [w][16t][16cix][6]

  const int tid = threadIdx.x;
  const int w = tid >> 6, l = tid & 63;
  const int cix = l & 15, lk = l >> 4;
  const f32x4 Z4 = {0.f, 0.f, 0.f, 0.f};

  *(uint64_t*)(ldsb + tid * 8) = 0ull;

  const int A0 = (cix == 0) ? (lk << 4) : 1024;   // bcast zero for cix>0
  const int col0 = w * 16 + cix, col1 = col0 + 128;
  const int oA00 = col0 * 2, oA10 = col1 * 2;
  float h00 = 0.f, h10 = 0.f;

#define AF_ZR(KT) (*(const bf16x8*)(ldsb + A0 + (KT) * 64))
#define AF_N(KT)  (*(const bf16x8*)(ldsb + A0 + (KT) * 64 + 2048))

  if (blockIdx.x < 128){
    // =================== layer 0 (producer) ===================
    const int r0 = blockIdx.x;
    const int chunkBase = blockIdx.x * 65536 + w * 16 + cix;
    bf16x8 wzr[4][8], wn[2][8];
#pragma unroll
    for (int i = 0; i < 4; i++)
#pragma unroll
      for (int kt = 0; kt < 8; kt++)
        wzr[i][kt] = *(const bf16x8*)(WZR0F + (size_t)((((w + 8 * i) * 8 + kt) * 64 + l) * 8));
#pragma unroll
    for (int i = 0; i < 2; i++)
#pragma unroll
      for (int kt = 0; kt < 8; kt++)
        wn[i][kt] = *(const bf16x8*)(WN0F + (size_t)((((w + 8 * i) * 8 + kt) * 64 + l) * 8));
    __syncthreads();

    bf16x4 rgA0{}, rgA1{};
    unsigned rgB0 = 0, rgB1 = 0;
    if (lk == 0){
      rgA0 = *(const bf16x4*)(GpA4 + (size_t)chunkBase * 4);
      rgB0 = GpB2[chunkBase];
      rgA1 = *(const bf16x4*)(GpA4 + (size_t)(chunkBase + 128) * 4);
      rgB1 = GpB2[chunkBase + 128];
    }

#define STEP0(T, RGA, RGB) do { \
    bf16x8 x0 = AF_ZR(0), x1 = AF_ZR(1), x2 = AF_ZR(2), x3 = AF_ZR(3); \
    f32x4 az0 = Z4, az1 = Z4, ar0 = Z4, ar1 = Z4; \
    __builtin_amdgcn_s_setprio(1); \
    az0 = MF(x0, wzr[0][0], az0); az1 = MF(x0, wzr[1][0], az1); \
    ar0 = MF(x0, wzr[2][0], ar0); ar1 = MF(x0, wzr[3][0], ar1); x0 = AF_ZR(4); \
    az0 = MF(x1, wzr[0][1], az0); az1 = MF(x1, wzr[1][1], az1); \
    ar0 = MF(x1, wzr[2][1], ar0); ar1 = MF(x1, wzr[3][1], ar1); x1 = AF_ZR(5); \
    az0 = MF(x2, wzr[0][2], az0); az1 = MF(x2, wzr[1][2], az1); \
    ar0 = MF(x2, wzr[2][2], ar0); ar1 = MF(x2, wzr[3][2], ar1); x2 = AF_ZR(6); \
    az0 = MF(x3, wzr[0][3], az0); az1 = MF(x3, wzr[1][3], az1); \
    ar0 = MF(x3, wzr[2][3], ar0); ar1 = MF(x3, wzr[3][3], ar1); x3 = AF_ZR(7); \
    az0 = MF(x0, wzr[0][4], az0); az1 = MF(x0, wzr[1][4], az1); \
    ar0 = MF(x0, wzr[2][4], ar0); ar1 = MF(x0, wzr[3][4], ar1); \
    az0 = MF(x1, wzr[0][5], az0); az1 = MF(x1, wzr[1][5], az1); \
    ar0 = MF(x1, wzr[2][5], ar0); ar1 = MF(x1, wzr[3][5], ar1); \
    az0 = MF(x2, wzr[0][6], az0); az1 = MF(x2, wzr[1][6], az1); \
    ar0 = MF(x2, wzr[2][6], ar0); ar1 = MF(x2, wzr[3][6], ar1); \
    az0 = MF(x3, wzr[0][7], az0); az1 = MF(x3, wzr[1][7], az1); \
    ar0 = MF(x3, wzr[2][7], ar0); ar1 = MF(x3, wzr[3][7], ar1); \
    __builtin_amdgcn_s_setprio(0); \
    float gn00 = 0.f, gn10 = 0.f, zv00 = 0.f, zv10 = 0.f; \
    if (lk == 0){ \
      float gz00 = bf2f((unsigned short)RGA[0]), gr00 = bf2f((unsigned short)RGA[1]); \
      gn00 = bf2f((unsigned short)RGA[2]); \
      float gz10 = bf2f((unsigned short)RGA[3]); \
      float gr10 = bf2f((unsigned short)(RGB & 0xffffu)); \
      gn10 = bf2f((unsigned short)(RGB >> 16)); \
      int tn = (T) + 2; if (tn >= S_) tn = (T); \
      size_t ch = (size_t)chunkBase + (size_t)tn * 128; \
      RGA = *(const bf16x4*)(GpA4 + ch * 4); \
      RGB = GpB2[ch]; \
      zv00 = sigmoidf_(az0[0] + gz00); zv10 = sigmoidf_(az1[0] + gz10); \
      float rv00 = sigmoidf_(ar0[0] + gr00), rv10 = sigmoidf_(ar1[0] + gr10); \
      *(short*)(ldsb + 2048 + oA00) = f2bf(rv00 * h00); \
      *(short*)(ldsb + 2048 + oA10) = f2bf(rv10 * h10); \
    } \
    bar_lds(); \
    bf16x8 y0 = AF_N(0), y1 = AF_N(1); \
    f32x4 an0 = Z4, an1 = Z4; \
    __builtin_amdgcn_s_setprio(1); \
    an0 = MF(y0, wn[0][0], an0); an1 = MF(y0, wn[1][0], an1); y0 = AF_N(2); \
    an0 = MF(y1, wn[0][1], an0); an1 = MF(y1, wn[1][1], an1); y1 = AF_N(3); \
    an0 = MF(y0, wn[0][2], an0); an1 = MF(y0, wn[1][2], an1); y0 = AF_N(4); \
    an0 = MF(y1, wn[0][3], an0); an1 = MF(y1, wn[1][3], an1); y1 = AF_N(5); \
    an0 = MF(y0, wn[0][4], an0); an1 = MF(y0, wn[1][4], an1); y0 = AF_N(6); \
    an0 = MF(y1, wn[0][5], an0); an1 = MF(y1, wn[1][5], an1); y1 = AF_N(7); \
    an0 = MF(y0, wn[0][6], an0); an1 = MF(y0, wn[1][6], an1); \
    an0 = MF(y1, wn[0][7], an0); an1 = MF(y1, wn[1][7], an1); \
    __builtin_amdgcn_s_setprio(0); \
    if (lk == 0){ \
      float nv00 = tanhf_(an0[0] + gn00), nv10 = tanhf_(an1[0] + gn10); \
      h00 = (1.f - zv00) * nv00 + zv00 * h00; \
      h10 = (1.f - zv10) * nv10 + zv10 * h10; \
      *(short*)(ldsb + oA00) = f2bf(h00); \
      *(short*)(ldsb + oA10) = f2bf(h10); \
      size_t ob = ((size_t)r0 * S_ + (T)) * H_; \
      pipe[ob + col0] = f2bf(h00); \
      pipe[ob + col1] = f2bf(h10); \
    } \
    bar_lds(); \
  } while (0)

#pragma unroll 1
    for (int t = 0; t < S_; t += 2){
      STEP0(t, rgA0, rgB0);
      STEP0(t + 1, rgA1, rgB1);
      if ((t & 15) == 14){
        __syncthreads();   // drains each wave's vmcnt: all pipe stores in L2
        if (tid == 0)
          __hip_atomic_store(&flags[r0], (unsigned)((t + 2) >> 4),
                             __ATOMIC_RELEASE, __HIP_MEMORY_SCOPE_AGENT);
      }
    }
#undef STEP0
    if (lk == 0){
      finals[(size_t)r0 * H_ + col0] = h00;
      finals[(size_t)r0 * H_ + col1] = h10;
    }
  } else {
    // =================== layer 1 (consumer) ===================
    const int b = blockIdx.x - 128;
    bf16x8 wzr[4][8];
#pragma unroll
    for (int i = 0; i < 4; i++)
#pragma unroll
      for (int kt = 0; kt < 8; kt++)
        wzr[i][kt] = *(const bf16x8*)(WZR1F + (size_t)((((w + 8 * i) * 8 + kt) * 64 + l) * 8));
#pragma unroll
    for (int i = 0; i < 2; i++)
#pragma unroll
      for (int kt = 0; kt < 8; kt++){
        bf16x8 v = *(const bf16x8*)(WN1F + (size_t)((((w + 8 * i) * 8 + kt) * 64 + l) * 8));
        *(bf16x8*)(wnL + (size_t)(((w * 2 + i) * 8 + kt) * 64 + l) * 8) = v;
      }
    __syncthreads();

    const short* wn0p = wnL + (size_t)(w * 2 + 0) * 8 * 512 + l * 8;
    const short* wn1p = wnL + (size_t)(w * 2 + 1) * 8 * 512 + l * 8;
#define WNL0(KT)  (*(const bf16x8*)(wn0p + (KT) * 512))
#define WNL1(KT)  (*(const bf16x8*)(wn1p + (KT) * 512))

    // W1top streamed frag bases: nt order [z0,r0,n0,z1,r1,n1]
    const short* wt0 = W1TF + (size_t)(w)      * 8 * 512 + l * 8;
    const short* wt1 = W1TF + (size_t)(16 + w) * 8 * 512 + l * 8;
    const short* wt2 = W1TF + (size_t)(32 + w) * 8 * 512 + l * 8;
    const short* wt3 = W1TF + (size_t)(8 + w)  * 8 * 512 + l * 8;
    const short* wt4 = W1TF + (size_t)(24 + w) * 8 * 512 + l * 8;
    const short* wt5 = W1TF + (size_t)(40 + w) * 8 * 512 + l * 8;
    float bb0 = bcat1[0 * 256 + 0 + w * 16 + cix];
    float bb1 = bcat1[1 * 256 + 0 + w * 16 + cix];
    float bb2 = bcat1[2 * 256 + 0 + w * 16 + cix];
    float bb3 = bcat1[0 * 256 + 128 + w * 16 + cix];
    float bb4 = bcat1[1 * 256 + 128 + w * 16 + cix];
    float bb5 = bcat1[2 * 256 + 128 + w * 16 + cix];
    short* p1Lw = p1L + w * 1536;   // 16t*16cix*6

#pragma unroll 1
    for (int c = 0; c < 32; c++){
      if (tid == 0){
        unsigned target = (unsigned)(c + 1);
        int guard = 0;
        while (__hip_atomic_load(&flags[b], __ATOMIC_ACQUIRE, __HIP_MEMORY_SCOPE_AGENT) < target){
          __builtin_amdgcn_s_sleep(4);
          if (++guard > (1 << 20)) break;   // bounded: logic bug -> wrong answer, not hang
        }
      }
      __syncthreads();

      // ---- P1 chunk GEMM: rows = 16 timesteps (full M), K=256, own 6 N-tiles
      const short* hp = pipe + ((size_t)b * 512 + c * 16 + cix) * 256 + lk * 8;
      f32x4 p0 = Z4, p1 = Z4, p2 = Z4, p3 = Z4, p4 = Z4, p5 = Z4;
      bf16x8 a0 = *(const bf16x8*)(hp + 0 * 32), a1 = *(const bf16x8*)(hp + 1 * 32);
      bf16x8 a2 = *(const bf16x8*)(hp + 2 * 32), a3 = *(const bf16x8*)(hp + 3 * 32);
      bf16x8 b0 = *(const bf16x8*)(wt0), b1 = *(const bf16x8*)(wt1), b2 = *(const bf16x8*)(wt2);
      bf16x8 b3 = *(const bf16x8*)(wt3), b4 = *(const bf16x8*)(wt4), b5 = *(const bf16x8*)(wt5);
#define GKT(AX, KTN) \
      p0 = MF(AX, b0, p0); b0 = *(const bf16x8*)(wt0 + (KTN) * 512); \
      p1 = MF(AX, b1, p1); b1 = *(const bf16x8*)(wt1 + (KTN) * 512); \
      p2 = MF(AX, b2, p2); b2 = *(const bf16x8*)(wt2 + (KTN) * 512); \
      p3 = MF(AX, b3, p3); b3 = *(const bf16x8*)(wt3 + (KTN) * 512); \
      p4 = MF(AX, b4, p4); b4 = *(const bf16x8*)(wt4 + (KTN) * 512); \
      p5 = MF(AX, b5, p5); b5 = *(const bf16x8*)(wt5 + (KTN) * 512);
#define GKTL(AX) \
      p0 = MF(AX, b0, p0); p1 = MF(AX, b1, p1); p2 = MF(AX, b2, p2); \
      p3 = MF(AX, b3, p3); p4 = MF(AX, b4, p4); p5 = MF(AX, b5, p5);
      GKT(a0, 1); a0 = *(const bf16x8*)(hp + 4 * 32);
      GKT(a1, 2); a1 = *(const bf16x8*)(hp + 5 * 32);
      GKT(a2, 3); a2 = *(const bf16x8*)(hp + 6 * 32);
      GKT(a3, 4); a3 = *(const bf16x8*)(hp + 7 * 32);
      GKT(a0, 5);
      GKT(a1, 6);
      GKT(a2, 7);
      GKTL(a3);
#undef GKT
#undef GKTL
      // ---- write P1 -> p1L (bf16 pairs), layout [t][cix][6]
#pragma unroll
      for (int r = 0; r < 4; r++){
        int tl = lk * 4 + r;
        int base = (tl * 16 + cix) * 6;
        unsigned u0 = (unsigned)(unsigned short)f2bf(p0[r]) | ((unsigned)(unsigned short)f2bf(p1[r]) << 16);
        unsigned u1 = (unsigned)(unsigned short)f2bf(p2[r]) | ((unsigned)(unsigned short)f2bf(p3[r]) << 16);
        unsigned u2 = (unsigned)(unsigned short)f2bf(p4[r]) | ((unsigned)(unsigned short)f2bf(p5[r]) << 16);
        *(unsigned*)(p1Lw + base)     = u0;
        *(unsigned*)(p1Lw + base + 2) = u1;
        *(unsigned*)(p1Lw + base + 4) = u2;
      }

      // ---- 16 recurrence steps
#pragma unroll 1
      for (int ts = 0; ts < 16; ts++){
        int T = c * 16 + ts;
        float gz00 = 0.f, gr00 = 0.f, gn00 = 0.f, gz10 = 0.f, gr10 = 0.f, gn10 = 0.f;
        if (lk == 0){
          const short* pb = p1Lw + (ts * 16 + cix) * 6;
          unsigned u0 = *(const unsigned*)(pb);
          unsigned u1 = *(const unsigned*)(pb + 2);
          unsigned u2 = *(const unsigned*)(pb + 4);
          gz00 = bf2f((unsigned short)(u0 & 0xffffu)) + bb0;
          gr00 = bf2f((unsigned short)(u0 >> 16)) + bb1;
          gn00 = bf2f((unsigned short)(u1 & 0xffffu)) + bb2;
          gz10 = bf2f((unsigned short)(u1 >> 16)) + bb3;
          gr10 = bf2f((unsigned short)(u2 & 0xffffu)) + bb4;
          gn10 = bf2f((unsigned short)(u2 >> 16)) + bb5;
        }
        bf16x8 x0 = AF_ZR(0), x1 = AF_ZR(1), x2 = AF_ZR(2), x3 = AF_ZR(3);
        f32x4 az0 = Z4, az1 = Z4, ar0 = Z4, ar1 = Z4;
        __builtin_amdgcn_s_setprio(1);
        az0 = MF(x0, wzr[0][0], az0); az1 = MF(x0, wzr[1][0], az1);
        ar0 = MF(x0, wzr[2][0], ar0); ar1 = MF(x0, wzr[3][0], ar1); x0 = AF_ZR(4);
        az0 = MF(x1, wzr[0][1], az0); az1 = MF(x1, wzr[1][1], az1);
        ar0 = MF(x1, wzr[2][1], ar0); ar1 = MF(x1, wzr[3][1], ar1); x1 = AF_ZR(5);
        az0 = MF(x2, wzr[0][2], az0); az1 = MF(x2, wzr[1][2], az1);
        ar0 = MF(x2, wzr[2][2], ar0); ar1 = MF(x2, wzr[3][2], ar1); x2 = AF_ZR(6);
        az0 = MF(x3, wzr[0][3], az0); az1 = MF(x3, wzr[1][3], az1);
        ar0 = MF(x3, wzr[2][3], ar0); ar1 = MF(x3, wzr[3][3], ar1); x3 = AF_ZR(7);
        az0 = MF(x0, wzr[0][4], az0); az1 = MF(x0, wzr[1][4], az1);
        ar0 = MF(x0, wzr[2][4], ar0); ar1 = MF(x0, wzr[3][4], ar1);
        az0 = MF(x1, wzr[0][5], az0); az1 = MF(x1, wzr[1][5], az1);
        ar0 = MF(x1, wzr[2][5], ar0); ar1 = MF(x1, wzr[3][5], ar1);
        az0 = MF(x2, wzr[0][6], az0); az1 = MF(x2, wzr[1][6], az1);
        ar0 = MF(x2, wzr[2][6], ar0); ar1 = MF(x2, wzr[3][6], ar1);
        az0 = MF(x3, wzr[0][7], az0); az1 = MF(x3, wzr[1][7], az1);
        ar0 = MF(x3, wzr[2][7], ar0); ar1 = MF(x3, wzr[3][7], ar1);
        __builtin_amdgcn_s_setprio(0);
        float zv00 = 0.f, zv10 = 0.f;
        if (lk == 0){
          zv00 = sigmoidf_(az0[0] + gz00); zv10 = sigmoidf_(az1[0] + gz10);
          float rv00 = sigmoidf_(ar0[0] + gr00), rv10 = sigmoidf_(ar1[0] + gr10);
          *(short*)(ldsb + 2048 + oA00) = f2bf(rv00 * h00);
          *(short*)(ldsb + 2048 + oA10) = f2bf(rv10 * h10);
        }
        bf16x8 w00 = WNL0(0), w10 = WNL1(0), w01 = WNL0(1), w11 = WNL1(1);
        bar_lds();
        bf16x8 y0 = AF_N(0), y1 = AF_N(1);
        f32x4 an0 = Z4, an1 = Z4;
        __builtin_amdgcn_s_setprio(1);
        an0 = MF(y0, w00, an0); an1 = MF(y0, w10, an1); y0 = AF_N(2); w00 = WNL0(2); w10 = WNL1(2);
        an0 = MF(y1, w01, an0); an1 = MF(y1, w11, an1); y1 = AF_N(3); w01 = WNL0(3); w11 = WNL1(3);
        an0 = MF(y0, w00, an0); an1 = MF(y0, w10, an1); y0 = AF_N(4); w00 = WNL0(4); w10 = WNL1(4);
        an0 = MF(y1, w01, an0); an1 = MF(y1, w11, an1); y1 = AF_N(5); w01 = WNL0(5); w11 = WNL1(5);
        an0 = MF(y0, w00, an0); an1 = MF(y0, w10, an1); y0 = AF_N(6); w00 = WNL0(6); w10 = WNL1(6);
        an0 = MF(y1, w01, an0); an1 = MF(y1, w11, an1); y1 = AF_N(7); w01 = WNL0(7); w11 = WNL1(7);
        an0 = MF(y0, w00, an0); an1 = MF(y0, w10, an1);
        an0 = MF(y1, w01, an0); an1 = MF(y1, w11, an1);
        __builtin_amdgcn_s_setprio(0);
        if (lk == 0){
          float nv00 = tanhf_(an0[0] + gn00), nv10 = tanhf_(an1[0] + gn10);
          h00 = (1.f - zv00) * nv00 + zv00 * h00;
          h10 = (1.f - zv10) * nv10 + zv10 * h10;
          *(short*)(ldsb + oA00) = f2bf(h00);
          *(short*)(ldsb + oA10) = f2bf(h10);
          size_t ob = ((size_t)b * S_ + T) * H_;
          out[ob + col0] = h00;
          out[ob + col1] = h10;
        }
        bar_lds();
      }
    }
#undef WNL0
#undef WNL1
    if (lk == 0){
      finals[32768 + (size_t)b * H_ + col0] = h00;
      finals[32768 + (size_t)b * H_ + col1] = h10;
    }
  }
#undef AF_ZR
#undef AF_N
}

// ---------------- launcher ----------------------------------------------------
extern "C" void kernel_launch(void* const* d_in, const int* in_sizes, int n_in,
                              void* d_out, int out_size, void* d_ws, size_t ws_size,
                              hipStream_t stream)
{
  (void)in_sizes; (void)n_in; (void)out_size; (void)ws_size;
  const float* x    = (const float*)d_in[0];
  const float* W_in = (const float*)d_in[1];
  const float* b_in = (const float*)d_in[2];
  const float* Wz   = (const float*)d_in[3];
  const float* bz   = (const float*)d_in[4];
  const float* Wr   = (const float*)d_in[5];
  const float* br   = (const float*)d_in[6];
  const float* Wn   = (const float*)d_in[7];
  const float* bn   = (const float*)d_in[8];
  float* out = (float*)d_out;

  char* ws = (char*)d_ws;
  short*    Gbuf  = (short*)(ws + 0);            // [65536][768] bf16 (96MB)
  short*    GpA4  = (short*)(ws + 100663296);    // 8.4M chunks * 8B (64MB)
  unsigned* GpB2  = (unsigned*)(ws + 167772160); // 8.4M chunks * 4B (32MB)
  float* WcT   = (float*)(ws + 201326592);
  float* bc    = (float*)(ws + 201719808);
  float* bcat1 = (float*)(ws + 201722880);
  short* WCF   = (short*)(ws + 201725952);
  short* W1TF  = (short*)(ws + 201922560);
  short* WZR0  = (short*)(ws + 202315776);
  short* WN0   = (short*)(ws + 202577920);
  short* WZR1  = (short*)(ws + 202708992);
  short* WN1   = (short*)(ws + 202971136);
  short* pipe  = (short*)(ws + 203102208);       // h0 bf16 [b][t][256] (32MB)
  unsigned* flags = (unsigned*)(ws + 236656640); // [128]

  prep_compute<<<390, 256, 0, stream>>>(W_in, b_in, Wz, bz, Wr, br, Wn, bn, WcT, bc, bcat1);
  pack_wc <<<384, 256, 0, stream>>>(WCF, WcT);
  pack_top<<<768, 256, 0, stream>>>(W1TF, Wz, Wr, Wn);
  pack_zr <<<512, 256, 0, stream>>>(WZR0, Wz, Wr, 0);
  pack_n  <<<256, 256, 0, stream>>>(WN0, Wn, 0);
  pack_zr <<<512, 256, 0, stream>>>(WZR1, Wz, Wr, 1);
  pack_n  <<<256, 256, 0, stream>>>(WN1, Wn, 1);

  gemm_g0<<<dim3(1024, 6), 256, 0, stream>>>(x, WCF, bc, Gbuf);
  repack6<<<32768, 256, 0, stream>>>((const unsigned short*)Gbuf, GpA4, GpB2);
  hipMemsetAsync(flags, 0, 128 * sizeof(unsigned), stream);
  fused_recur<<<256, 512, 0, stream>>>(GpA4, GpB2, WZR0, WN0, WZR1, WN1, W1TF, bcat1,
                                       pipe, out, out + 16777216, flags);
}